// Round 1
// baseline (1847.766 us; speedup 1.0000x reference)
//
#include <hip/hip_runtime.h>

#define NH 128
#define LAYERS 4

// ---------------- CSR build ----------------
__global__ void hist_kernel(const int* __restrict__ dst, int* __restrict__ deg, int E) {
    int e = blockIdx.x * blockDim.x + threadIdx.x;
    if (e < E) atomicAdd(&deg[dst[e]], 1);
}

__global__ __launch_bounds__(1024) void scan_kernel(const int* __restrict__ deg,
                                                    int* __restrict__ row_start,
                                                    int* __restrict__ cursor, int n) {
    __shared__ int part[1024];
    int t = threadIdx.x;
    int chunk = (n + 1023) >> 10;
    int begin = t * chunk;
    int end = min(begin + chunk, n);
    int s = 0;
    for (int i = begin; i < end; ++i) s += deg[i];
    part[t] = s;
    __syncthreads();
    for (int off = 1; off < 1024; off <<= 1) {
        int v = (t >= off) ? part[t - off] : 0;
        __syncthreads();
        part[t] += v;
        __syncthreads();
    }
    int run = (t == 0) ? 0 : part[t - 1];
    for (int i = begin; i < end; ++i) {
        row_start[i] = run;
        cursor[i] = run;
        run += deg[i];
    }
    if (t == 1023) row_start[n] = run;
}

__global__ void scatter_kernel(const int* __restrict__ src, const int* __restrict__ dst,
                               int* __restrict__ cursor, int2* __restrict__ pk, int E) {
    int e = blockIdx.x * blockDim.x + threadIdx.x;
    if (e < E) {
        int d = dst[e];
        int p = atomicAdd(&cursor[d], 1);
        pk[p] = make_int2(src[e], e);
    }
}

// ---------------- edge aggregation: x = h + sum_in(h[src] + eattr@We) + deg*be --------
__global__ __launch_bounds__(256) void aggregate_kernel(
    const float* __restrict__ h, const float* __restrict__ edge_attr,
    const int* __restrict__ row_start, const int2* __restrict__ pk,
    const float* __restrict__ We, const float* __restrict__ be,
    float* __restrict__ x, int N) {
    __shared__ float WeL[16 * NH];
    __shared__ float beL[NH];
    int t = threadIdx.x;
    for (int i = t; i < 16 * NH; i += 256) WeL[i] = We[i];
    if (t < NH) beL[t] = be[t];
    __syncthreads();

    int wave = t >> 6, lane = t & 63;
    int n = blockIdx.x * 4 + wave;
    if (n >= N) return;
    int c0 = lane, c1 = lane + 64;
    float acc0 = 0.f, acc1 = 0.f;
    int rs = row_start[n], re = row_start[n + 1];
    for (int p = rs; p < re; ++p) {
        int2 se = pk[p];
        int s = se.x, e = se.y;
        acc0 += h[s * NH + c0];
        acc1 += h[s * NH + c1];
        const float4* ea4 = (const float4*)(edge_attr + (size_t)e * 16);
        float4 a0 = ea4[0], a1 = ea4[1], a2 = ea4[2], a3 = ea4[3];
        float ea[16] = {a0.x, a0.y, a0.z, a0.w, a1.x, a1.y, a1.z, a1.w,
                        a2.x, a2.y, a2.z, a2.w, a3.x, a3.y, a3.z, a3.w};
#pragma unroll
        for (int k = 0; k < 16; ++k) {
            acc0 = fmaf(ea[k], WeL[k * NH + c0], acc0);
            acc1 = fmaf(ea[k], WeL[k * NH + c1], acc1);
        }
    }
    float degf = (float)(re - rs);
    x[(size_t)n * NH + c0] = h[(size_t)n * NH + c0] + acc0 + degf * beL[c0];
    x[(size_t)n * NH + c1] = h[(size_t)n * NH + c1] + acc1 + degf * beL[c1];
}

// ---------------- GEMM: Z = X @ W + b  (X: N x 128, W: 128 x 128) ---------------------
// 32 rows per block, 256 threads, each thread: 4 rows x 4 cols.
// Optional fused BN column stats (sum, sumsq) via atomics.
__global__ __launch_bounds__(256) void gemm128_kernel(
    const float* __restrict__ X, const float* __restrict__ W, const float* __restrict__ b,
    float* __restrict__ Z, int N, float* __restrict__ bnsum, float* __restrict__ bnsumsq) {
    __shared__ float Wl[64 * NH];   // half of W (32KB)
    __shared__ float Xl[32 * NH];   // X tile (16KB)
    int t = threadIdx.x;
    int row0 = blockIdx.x * 32;

    // stage X tile
    const float4* Xg4 = (const float4*)X;
    float4* Xl4 = (float4*)Xl;
    for (int i = t; i < 32 * 32; i += 256) {
        int r = i >> 5;
        int gr = row0 + r;
        Xl4[i] = (gr < N) ? Xg4[(size_t)gr * 32 + (i & 31)] : make_float4(0.f, 0.f, 0.f, 0.f);
    }

    int tcol = t & 31, trow = t >> 5;   // 32 col-quads x 8 row-groups
    float4 bias = ((const float4*)b)[tcol];
    float4 acc[4];
#pragma unroll
    for (int i = 0; i < 4; ++i) acc[i] = bias;

    float4* Wl4 = (float4*)Wl;
    const float4* Wg4 = (const float4*)W;
    for (int half = 0; half < 2; ++half) {
        __syncthreads();
        // stage 64 k-rows of W: 64*32 float4
        for (int i = t; i < 64 * 32; i += 256) Wl4[i] = Wg4[half * 64 * 32 + i];
        __syncthreads();
#pragma unroll 4
        for (int k4 = 0; k4 < 16; ++k4) {
            float4 w0 = Wl4[(k4 * 4 + 0) * 32 + tcol];
            float4 w1 = Wl4[(k4 * 4 + 1) * 32 + tcol];
            float4 w2 = Wl4[(k4 * 4 + 2) * 32 + tcol];
            float4 w3 = Wl4[(k4 * 4 + 3) * 32 + tcol];
#pragma unroll
            for (int i = 0; i < 4; ++i) {
                float4 a = Xl4[(trow * 4 + i) * 32 + half * 16 + k4];
                acc[i].x = fmaf(a.x, w0.x, fmaf(a.y, w1.x, fmaf(a.z, w2.x, fmaf(a.w, w3.x, acc[i].x))));
                acc[i].y = fmaf(a.x, w0.y, fmaf(a.y, w1.y, fmaf(a.z, w2.y, fmaf(a.w, w3.y, acc[i].y))));
                acc[i].z = fmaf(a.x, w0.z, fmaf(a.y, w1.z, fmaf(a.z, w2.z, fmaf(a.w, w3.z, acc[i].z))));
                acc[i].w = fmaf(a.x, w0.w, fmaf(a.y, w1.w, fmaf(a.z, w2.w, fmaf(a.w, w3.w, acc[i].w))));
            }
        }
    }

    // store
#pragma unroll
    for (int i = 0; i < 4; ++i) {
        int gr = row0 + trow * 4 + i;
        if (gr < N) ((float4*)Z)[(size_t)gr * 32 + tcol] = acc[i];
    }

    // fused BN column stats
    if (bnsum) {
        float4 s = make_float4(0.f, 0.f, 0.f, 0.f), q = make_float4(0.f, 0.f, 0.f, 0.f);
#pragma unroll
        for (int i = 0; i < 4; ++i) {
            int gr = row0 + trow * 4 + i;
            if (gr < N) {
                s.x += acc[i].x; s.y += acc[i].y; s.z += acc[i].z; s.w += acc[i].w;
                q.x += acc[i].x * acc[i].x; q.y += acc[i].y * acc[i].y;
                q.z += acc[i].z * acc[i].z; q.w += acc[i].w * acc[i].w;
            }
        }
        __syncthreads();
        ((float4*)Xl)[trow * 32 + tcol] = s;              // [8][128] sums
        ((float4*)(Xl + 8 * NH))[trow * 32 + tcol] = q;   // [8][128] sumsq
        __syncthreads();
        if (t < NH) {
            float ss = 0.f, qq = 0.f;
#pragma unroll
            for (int r = 0; r < 8; ++r) {
                ss += Xl[r * NH + t];
                qq += Xl[8 * NH + r * NH + t];
            }
            atomicAdd(&bnsum[t], ss);
            atomicAdd(&bnsumsq[t], qq);
        }
    }
}

// ---------------- BN finalize: per-channel scale/shift -------------------------------
__global__ void bnfinal_kernel(const float* __restrict__ bnsum, const float* __restrict__ bnsumsq,
                               const float* __restrict__ gamma, const float* __restrict__ beta,
                               float* __restrict__ scale, float* __restrict__ shift, float invN) {
    int c = threadIdx.x;
    float mu = bnsum[c] * invN;
    float var = bnsumsq[c] * invN - mu * mu;
    float sc = gamma[c] * rsqrtf(var + 1e-5f);
    scale[c] = sc;
    shift[c] = beta[c] - mu * sc;
}

// ---------------- h = relu(z*scale+shift) + h; pooled[batch[n]] += h -----------------
__global__ __launch_bounds__(256) void update_pool_kernel(
    const float* __restrict__ z, float* __restrict__ h, const int* __restrict__ batch,
    const float* __restrict__ scale, const float* __restrict__ shift,
    float* __restrict__ pooled, int N) {
    int idx = blockIdx.x * 256 + threadIdx.x;   // float4 index over N*32
    if (idx >= N * 32) return;
    int n = idx >> 5, q = idx & 31;
    float4 zv = ((const float4*)z)[idx];
    float4 sc = ((const float4*)scale)[q];
    float4 sh = ((const float4*)shift)[q];
    float4 hv = ((const float4*)h)[idx];
    float4 r;
    r.x = fmaxf(fmaf(zv.x, sc.x, sh.x), 0.f) + hv.x;
    r.y = fmaxf(fmaf(zv.y, sc.y, sh.y), 0.f) + hv.y;
    r.z = fmaxf(fmaf(zv.z, sc.z, sh.z), 0.f) + hv.z;
    r.w = fmaxf(fmaf(zv.w, sc.w, sh.w), 0.f) + hv.w;
    ((float4*)h)[idx] = r;
    float* pg = pooled + (size_t)batch[n] * NH + q * 4;
    atomicAdd(pg + 0, r.x);
    atomicAdd(pg + 1, r.y);
    atomicAdd(pg + 2, r.z);
    atomicAdd(pg + 3, r.w);
}

__global__ __launch_bounds__(256) void pool0_kernel(
    const float* __restrict__ h, const int* __restrict__ batch,
    float* __restrict__ pooled, int N) {
    int idx = blockIdx.x * 256 + threadIdx.x;
    if (idx >= N * 32) return;
    int n = idx >> 5, q = idx & 31;
    float4 hv = ((const float4*)h)[idx];
    float* pg = pooled + (size_t)batch[n] * NH + q * 4;
    atomicAdd(pg + 0, hv.x);
    atomicAdd(pg + 1, hv.y);
    atomicAdd(pg + 2, hv.z);
    atomicAdd(pg + 3, hv.w);
}

// ---------------- JK head: out[g,c] = sum_l (pooled_l[g] . jkW_l[:,c] + jkb_l[c]) ----
__global__ void jk_kernel(const float* __restrict__ pooled, const float* __restrict__ jkW,
                          const float* __restrict__ jkb, float* __restrict__ out, int G) {
    int idx = blockIdx.x * blockDim.x + threadIdx.x;
    if (idx >= G * 10) return;
    int g = idx / 10, c = idx % 10;
    float acc = 0.f;
    for (int l = 0; l < LAYERS + 1; ++l) {
        acc += jkb[l * 10 + c];
        const float* pg = pooled + ((size_t)l * G + g) * NH;
        const float* wl = jkW + (size_t)l * NH * 10 + c;
        float s = 0.f;
#pragma unroll 16
        for (int k = 0; k < NH; ++k) s = fmaf(pg[k], wl[k * 10], s);
        acc += s;
    }
    out[idx] = acc;
}

extern "C" void kernel_launch(void* const* d_in, const int* in_sizes, int n_in,
                              void* d_out, int out_size, void* d_ws, size_t ws_size,
                              hipStream_t stream) {
    const float* h_in      = (const float*)d_in[0];
    const float* edge_attr = (const float*)d_in[1];
    const int*   edge_idx  = (const int*)d_in[2];
    const int*   batch     = (const int*)d_in[5];
    const float* emb_W     = (const float*)d_in[6];
    const float* emb_b     = (const float*)d_in[7];
    const float* conv_W    = (const float*)d_in[8];
    const float* conv_b    = (const float*)d_in[9];
    const float* conv_We   = (const float*)d_in[10];
    const float* conv_be   = (const float*)d_in[11];
    const float* bn_gamma  = (const float*)d_in[12];
    const float* bn_beta   = (const float*)d_in[13];
    const float* jk_W      = (const float*)d_in[14];
    const float* jk_b      = (const float*)d_in[15];
    float* out = (float*)d_out;

    const int N = in_sizes[0] / NH;
    const int E = in_sizes[1] / 16;
    const int G = out_size / 10;

    const int* src = edge_idx;
    const int* dst = edge_idx + E;

    // workspace layout
    size_t off = 0;
    auto alloc = [&](size_t bytes) -> void* {
        void* p = (char*)d_ws + off;
        off += (bytes + 255) & ~(size_t)255;
        return p;
    };
    float* hbuf = (float*)alloc((size_t)N * NH * 4);
    float* xbuf = (float*)alloc((size_t)N * NH * 4);
    float* zbuf = (float*)alloc((size_t)N * NH * 4);
    size_t zero_off = off;
    float* pooled  = (float*)alloc((size_t)(LAYERS + 1) * G * NH * 4);
    float* bnsum   = (float*)alloc((size_t)LAYERS * NH * 4);
    float* bnsumsq = (float*)alloc((size_t)LAYERS * NH * 4);
    int* deg       = (int*)alloc((size_t)N * 4);
    size_t zero_bytes = off - zero_off;
    float* scale = (float*)alloc(NH * 4);
    float* shift = (float*)alloc(NH * 4);
    int* row_start = (int*)alloc((size_t)(N + 1) * 4);
    int* cursor    = (int*)alloc((size_t)N * 4);
    int2* pk       = (int2*)alloc((size_t)E * 8);
    (void)ws_size; (void)n_in;

    hipMemsetAsync((char*)d_ws + zero_off, 0, zero_bytes, stream);

    // CSR build by dst
    hist_kernel<<<(E + 255) / 256, 256, 0, stream>>>(dst, deg, E);
    scan_kernel<<<1, 1024, 0, stream>>>(deg, row_start, cursor, N);
    scatter_kernel<<<(E + 255) / 256, 256, 0, stream>>>(src, dst, cursor, pk, E);

    dim3 gemm_grid((N + 31) / 32);
    dim3 agg_grid((N + 3) / 4);
    dim3 ew_grid((N * 32 + 255) / 256);

    // embedding: h0 = h_in @ emb_W + emb_b ; pool into pooled[0]
    gemm128_kernel<<<gemm_grid, 256, 0, stream>>>(h_in, emb_W, emb_b, hbuf, N, nullptr, nullptr);
    pool0_kernel<<<ew_grid, 256, 0, stream>>>(hbuf, batch, pooled, N);

    for (int l = 0; l < LAYERS; ++l) {
        aggregate_kernel<<<agg_grid, 256, 0, stream>>>(
            hbuf, edge_attr, row_start, pk,
            conv_We + (size_t)l * 16 * NH, conv_be + (size_t)l * NH, xbuf, N);
        gemm128_kernel<<<gemm_grid, 256, 0, stream>>>(
            xbuf, conv_W + (size_t)l * NH * NH, conv_b + (size_t)l * NH, zbuf, N,
            bnsum + (size_t)l * NH, bnsumsq + (size_t)l * NH);
        bnfinal_kernel<<<1, NH, 0, stream>>>(
            bnsum + (size_t)l * NH, bnsumsq + (size_t)l * NH,
            bn_gamma + (size_t)l * NH, bn_beta + (size_t)l * NH,
            scale, shift, 1.0f / (float)N);
        update_pool_kernel<<<ew_grid, 256, 0, stream>>>(
            zbuf, hbuf, batch, scale, shift, pooled + (size_t)(l + 1) * G * NH, N);
    }

    jk_kernel<<<(G * 10 + 255) / 256, 256, 0, stream>>>(pooled, jk_W, jk_b, out, G);
}

// Round 2
// 1079.530 us; speedup vs baseline: 1.7116x; 1.7116x over previous
//
#include <hip/hip_runtime.h>

#define NH 128
#define LAYERS 4

// ---------------- generic histogram ----------------
__global__ void hist_kernel(const int* __restrict__ idx, int* __restrict__ cnt, int n) {
    int i = blockIdx.x * blockDim.x + threadIdx.x;
    if (i < n) atomicAdd(&cnt[idx[i]], 1);
}

// ---------------- single-block exclusive scan (deg -> starts, cursor) ----------------
__global__ __launch_bounds__(1024) void scan_kernel(const int* __restrict__ deg,
                                                    int* __restrict__ row_start,
                                                    int* __restrict__ cursor, int n) {
    __shared__ int part[1024];
    int t = threadIdx.x;
    int chunk = (n + 1023) >> 10;
    int begin = t * chunk;
    int end = min(begin + chunk, n);
    int s = 0;
    for (int i = begin; i < end; ++i) s += deg[i];
    part[t] = s;
    __syncthreads();
    for (int off = 1; off < 1024; off <<= 1) {
        int v = (t >= off) ? part[t - off] : 0;
        __syncthreads();
        part[t] += v;
        __syncthreads();
    }
    int run = (t == 0) ? 0 : part[t - 1];
    for (int i = begin; i < end; ++i) {
        row_start[i] = run;
        cursor[i] = run;
        run += deg[i];
    }
    if (t == 1023) row_start[n] = part[1023];
}

__global__ void scatter_kernel(const int* __restrict__ src, const int* __restrict__ dst,
                               int* __restrict__ cursor, int* __restrict__ srcP,
                               int* __restrict__ eidP, int E) {
    int e = blockIdx.x * blockDim.x + threadIdx.x;
    if (e < E) {
        int d = dst[e];
        int p = atomicAdd(&cursor[d], 1);
        srcP[p] = src[e];
        eidP[p] = e;
    }
}

// ---------------- easum[n][k] = sum over in-edges of edge_attr[e][k] (layer-invariant)
__global__ __launch_bounds__(256) void easum_kernel(const float* __restrict__ edge_attr,
                                                    const int* __restrict__ eidP,
                                                    const int* __restrict__ row_start,
                                                    float* __restrict__ easum, int N) {
    int t = threadIdx.x;
    int node = blockIdx.x * 16 + (t >> 4);
    int k = t & 15;
    if (node >= N) return;
    int rs = row_start[node], re = row_start[node + 1];
    float acc = 0.f;
    for (int p = rs; p < re; ++p)
        acc += edge_attr[(size_t)eidP[p] * 16 + k];
    easum[node * 16 + k] = acc;
}

// ---------------- x = h + sum_in h[src] + easum@We + deg*be --------------------------
__global__ __launch_bounds__(256) void aggregate_kernel(
    const float* __restrict__ h, const int* __restrict__ srcP,
    const int* __restrict__ row_start, const float* __restrict__ easum,
    const float* __restrict__ We, const float* __restrict__ be,
    float* __restrict__ x, int N) {
    __shared__ float2 WeL[16 * 64];
    int t = threadIdx.x;
    const float2* Wg2 = (const float2*)We;
    for (int i = t; i < 16 * 64; i += 256) WeL[i] = Wg2[i];
    __syncthreads();

    int wave = t >> 6, lane = t & 63;
    int n = blockIdx.x * 4 + wave;
    if (n >= N) return;
    const float2* h2 = (const float2*)h;
    float2 acc = h2[(size_t)n * 64 + lane];   // self term
    int rs = row_start[n], re = row_start[n + 1];
    float myea = (lane < 16) ? easum[n * 16 + lane] : 0.f;

    for (int base = rs; base < re; base += 64) {
        int cnt = min(64, re - base);
        int myS = (base + lane < re) ? srcP[base + lane] : 0;
        int j = 0;
        for (; j + 3 < cnt; j += 4) {
            int s0 = __shfl(myS, j);
            int s1 = __shfl(myS, j + 1);
            int s2 = __shfl(myS, j + 2);
            int s3 = __shfl(myS, j + 3);
            float2 a0 = h2[(size_t)s0 * 64 + lane];
            float2 a1 = h2[(size_t)s1 * 64 + lane];
            float2 a2 = h2[(size_t)s2 * 64 + lane];
            float2 a3 = h2[(size_t)s3 * 64 + lane];
            acc.x += (a0.x + a1.x) + (a2.x + a3.x);
            acc.y += (a0.y + a1.y) + (a2.y + a3.y);
        }
        for (; j < cnt; ++j) {
            int s = __shfl(myS, j);
            float2 a = h2[(size_t)s * 64 + lane];
            acc.x += a.x;
            acc.y += a.y;
        }
    }

    float degf = (float)(re - rs);
    float2 be2 = ((const float2*)be)[lane];
#pragma unroll
    for (int k = 0; k < 16; ++k) {
        float e = __shfl(myea, k);
        float2 w = WeL[k * 64 + lane];
        acc.x = fmaf(e, w.x, acc.x);
        acc.y = fmaf(e, w.y, acc.y);
    }
    acc.x += degf * be2.x;
    acc.y += degf * be2.y;
    ((float2*)x)[(size_t)n * 64 + lane] = acc;
}

// ---------------- GEMM: Z = X @ W + b  (X: N x 128, W: 128 x 128) ---------------------
__global__ __launch_bounds__(256) void gemm128_kernel(
    const float* __restrict__ X, const float* __restrict__ W, const float* __restrict__ b,
    float* __restrict__ Z, int N, float* __restrict__ bnsum, float* __restrict__ bnsumsq) {
    __shared__ float Wl[64 * NH];   // half of W (32KB)
    __shared__ float Xl[32 * NH];   // X tile (16KB)
    int t = threadIdx.x;
    int row0 = blockIdx.x * 32;

    const float4* Xg4 = (const float4*)X;
    float4* Xl4 = (float4*)Xl;
    for (int i = t; i < 32 * 32; i += 256) {
        int r = i >> 5;
        int gr = row0 + r;
        Xl4[i] = (gr < N) ? Xg4[(size_t)gr * 32 + (i & 31)] : make_float4(0.f, 0.f, 0.f, 0.f);
    }

    int tcol = t & 31, trow = t >> 5;
    float4 bias = ((const float4*)b)[tcol];
    float4 acc[4];
#pragma unroll
    for (int i = 0; i < 4; ++i) acc[i] = bias;

    float4* Wl4 = (float4*)Wl;
    const float4* Wg4 = (const float4*)W;
    for (int half = 0; half < 2; ++half) {
        __syncthreads();
        for (int i = t; i < 64 * 32; i += 256) Wl4[i] = Wg4[half * 64 * 32 + i];
        __syncthreads();
#pragma unroll 4
        for (int k4 = 0; k4 < 16; ++k4) {
            float4 w0 = Wl4[(k4 * 4 + 0) * 32 + tcol];
            float4 w1 = Wl4[(k4 * 4 + 1) * 32 + tcol];
            float4 w2 = Wl4[(k4 * 4 + 2) * 32 + tcol];
            float4 w3 = Wl4[(k4 * 4 + 3) * 32 + tcol];
#pragma unroll
            for (int i = 0; i < 4; ++i) {
                float4 a = Xl4[(trow * 4 + i) * 32 + half * 16 + k4];
                acc[i].x = fmaf(a.x, w0.x, fmaf(a.y, w1.x, fmaf(a.z, w2.x, fmaf(a.w, w3.x, acc[i].x))));
                acc[i].y = fmaf(a.x, w0.y, fmaf(a.y, w1.y, fmaf(a.z, w2.y, fmaf(a.w, w3.y, acc[i].y))));
                acc[i].z = fmaf(a.x, w0.z, fmaf(a.y, w1.z, fmaf(a.z, w2.z, fmaf(a.w, w3.z, acc[i].z))));
                acc[i].w = fmaf(a.x, w0.w, fmaf(a.y, w1.w, fmaf(a.z, w2.w, fmaf(a.w, w3.w, acc[i].w))));
            }
        }
    }

#pragma unroll
    for (int i = 0; i < 4; ++i) {
        int gr = row0 + trow * 4 + i;
        if (gr < N) ((float4*)Z)[(size_t)gr * 32 + tcol] = acc[i];
    }

    if (bnsum) {
        float4 s = make_float4(0.f, 0.f, 0.f, 0.f), q = make_float4(0.f, 0.f, 0.f, 0.f);
#pragma unroll
        for (int i = 0; i < 4; ++i) {
            int gr = row0 + trow * 4 + i;
            if (gr < N) {
                s.x += acc[i].x; s.y += acc[i].y; s.z += acc[i].z; s.w += acc[i].w;
                q.x += acc[i].x * acc[i].x; q.y += acc[i].y * acc[i].y;
                q.z += acc[i].z * acc[i].z; q.w += acc[i].w * acc[i].w;
            }
        }
        __syncthreads();
        ((float4*)Xl)[trow * 32 + tcol] = s;
        ((float4*)(Xl + 8 * NH))[trow * 32 + tcol] = q;
        __syncthreads();
        if (t < NH) {
            float ss = 0.f, qq = 0.f;
#pragma unroll
            for (int r = 0; r < 8; ++r) {
                ss += Xl[r * NH + t];
                qq += Xl[8 * NH + r * NH + t];
            }
            atomicAdd(&bnsum[t], ss);
            atomicAdd(&bnsumsq[t], qq);
        }
    }
}

// ---------------- BN finalize ---------------------------------------------------------
__global__ void bnfinal_kernel(const float* __restrict__ bnsum, const float* __restrict__ bnsumsq,
                               const float* __restrict__ gamma, const float* __restrict__ beta,
                               float* __restrict__ scale, float* __restrict__ shift, float invN) {
    int c = threadIdx.x;
    float mu = bnsum[c] * invN;
    float var = bnsumsq[c] * invN - mu * mu;
    float sc = gamma[c] * rsqrtf(var + 1e-5f);
    scale[c] = sc;
    shift[c] = beta[c] - mu * sc;
}

// ---------------- h = relu(z*scale+shift) + h (pure elementwise) ---------------------
__global__ __launch_bounds__(256) void update_kernel(
    const float* __restrict__ z, float* __restrict__ h,
    const float* __restrict__ scale, const float* __restrict__ shift, int total4) {
    int idx = blockIdx.x * 256 + threadIdx.x;
    if (idx >= total4) return;
    int q = idx & 31;
    float4 zv = ((const float4*)z)[idx];
    float4 sc = ((const float4*)scale)[q];
    float4 sh = ((const float4*)shift)[q];
    float4 hv = ((const float4*)h)[idx];
    float4 r;
    r.x = fmaxf(fmaf(zv.x, sc.x, sh.x), 0.f) + hv.x;
    r.y = fmaxf(fmaf(zv.y, sc.y, sh.y), 0.f) + hv.y;
    r.z = fmaxf(fmaf(zv.z, sc.z, sh.z), 0.f) + hv.z;
    r.w = fmaxf(fmaf(zv.w, sc.w, sh.w), 0.f) + hv.w;
    ((float4*)h)[idx] = r;
}

// ---------------- pool: block per graph, batch is sorted -> no atomics ---------------
__global__ __launch_bounds__(256) void pool_kernel(
    const float* __restrict__ h, const int* __restrict__ gstart,
    float* __restrict__ pooled, int G) {
    int g = blockIdx.x;
    int t = threadIdx.x;
    int s = gstart[g], e = gstart[g + 1];
    int c = t & 127, half = t >> 7;
    float acc = 0.f;
    for (int n = s + half; n < e; n += 2)
        acc += h[(size_t)n * NH + c];
    __shared__ float red[256];
    red[t] = acc;
    __syncthreads();
    if (t < NH) pooled[(size_t)g * NH + t] = red[t] + red[t + NH];
}

// ---------------- JK head -------------------------------------------------------------
__global__ void jk_kernel(const float* __restrict__ pooled, const float* __restrict__ jkW,
                          const float* __restrict__ jkb, float* __restrict__ out, int G) {
    int idx = blockIdx.x * blockDim.x + threadIdx.x;
    if (idx >= G * 10) return;
    int g = idx / 10, c = idx % 10;
    float acc = 0.f;
    for (int l = 0; l < LAYERS + 1; ++l) {
        acc += jkb[l * 10 + c];
        const float* pg = pooled + ((size_t)l * G + g) * NH;
        const float* wl = jkW + (size_t)l * NH * 10 + c;
        float s = 0.f;
#pragma unroll 16
        for (int k = 0; k < NH; ++k) s = fmaf(pg[k], wl[k * 10], s);
        acc += s;
    }
    out[idx] = acc;
}

extern "C" void kernel_launch(void* const* d_in, const int* in_sizes, int n_in,
                              void* d_out, int out_size, void* d_ws, size_t ws_size,
                              hipStream_t stream) {
    const float* h_in      = (const float*)d_in[0];
    const float* edge_attr = (const float*)d_in[1];
    const int*   edge_idx  = (const int*)d_in[2];
    const int*   batch     = (const int*)d_in[5];
    const float* emb_W     = (const float*)d_in[6];
    const float* emb_b     = (const float*)d_in[7];
    const float* conv_W    = (const float*)d_in[8];
    const float* conv_b    = (const float*)d_in[9];
    const float* conv_We   = (const float*)d_in[10];
    const float* conv_be   = (const float*)d_in[11];
    const float* bn_gamma  = (const float*)d_in[12];
    const float* bn_beta   = (const float*)d_in[13];
    const float* jk_W      = (const float*)d_in[14];
    const float* jk_b      = (const float*)d_in[15];
    float* out = (float*)d_out;

    const int N = in_sizes[0] / NH;
    const int E = in_sizes[1] / 16;
    const int G = out_size / 10;

    const int* src = edge_idx;
    const int* dst = edge_idx + E;

    size_t off = 0;
    auto alloc = [&](size_t bytes) -> void* {
        void* p = (char*)d_ws + off;
        off += (bytes + 255) & ~(size_t)255;
        return p;
    };
    float* hbuf = (float*)alloc((size_t)N * NH * 4);
    float* xbuf = (float*)alloc((size_t)N * NH * 4);
    float* zbuf = (float*)alloc((size_t)N * NH * 4);
    float* pooled  = (float*)alloc((size_t)(LAYERS + 1) * G * NH * 4);
    float* easum   = (float*)alloc((size_t)N * 16 * 4);
    size_t zero_off = off;
    float* bnsum   = (float*)alloc((size_t)LAYERS * NH * 4);
    float* bnsumsq = (float*)alloc((size_t)LAYERS * NH * 4);
    int* deg       = (int*)alloc((size_t)N * 4);
    int* gdeg      = (int*)alloc((size_t)G * 4);
    size_t zero_bytes = off - zero_off;
    float* scale   = (float*)alloc(NH * 4);
    float* shift   = (float*)alloc(NH * 4);
    int* row_start = (int*)alloc((size_t)(N + 1) * 4);
    int* cursor    = (int*)alloc((size_t)N * 4);
    int* gstart    = (int*)alloc((size_t)(G + 1) * 4);
    int* gcursor   = (int*)alloc((size_t)G * 4);
    int* srcP      = (int*)alloc((size_t)E * 4);
    int* eidP      = (int*)alloc((size_t)E * 4);
    (void)ws_size; (void)n_in;

    hipMemsetAsync((char*)d_ws + zero_off, 0, zero_bytes, stream);

    // CSR by dst + graph starts from sorted batch
    hist_kernel<<<(E + 255) / 256, 256, 0, stream>>>(dst, deg, E);
    hist_kernel<<<(N + 255) / 256, 256, 0, stream>>>(batch, gdeg, N);
    scan_kernel<<<1, 1024, 0, stream>>>(deg, row_start, cursor, N);
    scan_kernel<<<1, 1024, 0, stream>>>(gdeg, gstart, gcursor, G);
    scatter_kernel<<<(E + 255) / 256, 256, 0, stream>>>(src, dst, cursor, srcP, eidP, E);
    easum_kernel<<<(N + 15) / 16, 256, 0, stream>>>(edge_attr, eidP, row_start, easum, N);

    dim3 gemm_grid((N + 31) / 32);
    dim3 agg_grid((N + 3) / 4);
    dim3 ew_grid((N * 32 + 255) / 256);

    gemm128_kernel<<<gemm_grid, 256, 0, stream>>>(h_in, emb_W, emb_b, hbuf, N, nullptr, nullptr);
    pool_kernel<<<G, 256, 0, stream>>>(hbuf, gstart, pooled, G);

    for (int l = 0; l < LAYERS; ++l) {
        aggregate_kernel<<<agg_grid, 256, 0, stream>>>(
            hbuf, srcP, row_start, easum,
            conv_We + (size_t)l * 16 * NH, conv_be + (size_t)l * NH, xbuf, N);
        gemm128_kernel<<<gemm_grid, 256, 0, stream>>>(
            xbuf, conv_W + (size_t)l * NH * NH, conv_b + (size_t)l * NH, zbuf, N,
            bnsum + (size_t)l * NH, bnsumsq + (size_t)l * NH);
        bnfinal_kernel<<<1, NH, 0, stream>>>(
            bnsum + (size_t)l * NH, bnsumsq + (size_t)l * NH,
            bn_gamma + (size_t)l * NH, bn_beta + (size_t)l * NH,
            scale, shift, 1.0f / (float)N);
        update_kernel<<<ew_grid, 256, 0, stream>>>(zbuf, hbuf, scale, shift, N * 32);
        pool_kernel<<<G, 256, 0, stream>>>(hbuf, gstart, pooled + (size_t)(l + 1) * G * NH, G);
    }

    jk_kernel<<<(G * 10 + 255) / 256, 256, 0, stream>>>(pooled, jk_W, jk_b, out, G);
}

// Round 3
// 940.187 us; speedup vs baseline: 1.9653x; 1.1482x over previous
//
#include <hip/hip_runtime.h>

#define NH 128
#define LAYERS 4

// ---------------- histogram (edge dst degrees) ----------------
__global__ void hist_kernel(const int* __restrict__ idx, int* __restrict__ cnt, int n) {
    int i = blockIdx.x * blockDim.x + threadIdx.x;
    if (i < n) atomicAdd(&cnt[idx[i]], 1);
}

// ---------------- gstart from sorted batch: boundary detection ----------------
__global__ void gstart_kernel(const int* __restrict__ batch, int* __restrict__ gstart,
                              int N, int G) {
    int i = blockIdx.x * blockDim.x + threadIdx.x;
    if (i >= N) return;
    int b = batch[i];
    int prev = (i == 0) ? -1 : batch[i - 1];
    for (int g = prev + 1; g <= b; ++g) gstart[g] = i;
    if (i == N - 1)
        for (int g = b + 1; g <= G; ++g) gstart[g] = N;
}

// ---------------- hierarchical scan: phase A (1024 elems/block -> bsum) --------------
__global__ __launch_bounds__(256) void block_sum_kernel(const int* __restrict__ deg,
                                                        int* __restrict__ bsum, int n) {
    __shared__ int red[256];
    int t = threadIdx.x;
    int base = blockIdx.x * 1024;
    int s = 0;
#pragma unroll
    for (int i = 0; i < 4; ++i) {
        int idx = base + i * 256 + t;
        if (idx < n) s += deg[idx];
    }
    red[t] = s;
    __syncthreads();
    for (int off = 128; off > 0; off >>= 1) {
        if (t < off) red[t] += red[t + off];
        __syncthreads();
    }
    if (t == 0) bsum[blockIdx.x] = red[0];
}

// ---------------- phase B: single-block scan of partials (nb <= 1024) ----------------
__global__ __launch_bounds__(1024) void scan_partials_kernel(int* __restrict__ bsum, int nb,
                                                             int* __restrict__ row_start, int n) {
    __shared__ int part[1024];
    int t = threadIdx.x;
    int v = (t < nb) ? bsum[t] : 0;
    part[t] = v;
    __syncthreads();
    for (int off = 1; off < 1024; off <<= 1) {
        int u = (t >= off) ? part[t - off] : 0;
        __syncthreads();
        part[t] += u;
        __syncthreads();
    }
    if (t < nb) bsum[t] = part[t] - v;          // exclusive
    if (t == 1023) row_start[n] = part[1023];   // total
}

// ---------------- phase C: local scan + global offset -> row_start, cursor -----------
__global__ __launch_bounds__(256) void local_scan_kernel(const int* __restrict__ deg,
                                                         const int* __restrict__ bsum,
                                                         int* __restrict__ row_start,
                                                         int* __restrict__ cursor, int n) {
    __shared__ int part[256];
    int t = threadIdx.x;
    int base = blockIdx.x * 1024 + t * 4;
    int v0 = 0, v1 = 0, v2 = 0, v3 = 0;
    if (base + 3 < n) {
        int4 v = *(const int4*)(deg + base);
        v0 = v.x; v1 = v.y; v2 = v.z; v3 = v.w;
    } else {
        if (base + 0 < n) v0 = deg[base + 0];
        if (base + 1 < n) v1 = deg[base + 1];
        if (base + 2 < n) v2 = deg[base + 2];
        if (base + 3 < n) v3 = deg[base + 3];
    }
    int tsum = v0 + v1 + v2 + v3;
    part[t] = tsum;
    __syncthreads();
    for (int off = 1; off < 256; off <<= 1) {
        int u = (t >= off) ? part[t - off] : 0;
        __syncthreads();
        part[t] += u;
        __syncthreads();
    }
    int run = bsum[blockIdx.x] + part[t] - tsum;
    int r0 = run, r1 = run + v0, r2 = r1 + v1, r3 = r2 + v2;
    if (base + 3 < n) {
        *(int4*)(row_start + base) = make_int4(r0, r1, r2, r3);
        *(int4*)(cursor + base) = make_int4(r0, r1, r2, r3);
    } else {
        if (base + 0 < n) { row_start[base + 0] = r0; cursor[base + 0] = r0; }
        if (base + 1 < n) { row_start[base + 1] = r1; cursor[base + 1] = r1; }
        if (base + 2 < n) { row_start[base + 2] = r2; cursor[base + 2] = r2; }
        if (base + 3 < n) { row_start[base + 3] = r3; cursor[base + 3] = r3; }
    }
}

__global__ void scatter_kernel(const int* __restrict__ src, const int* __restrict__ dst,
                               int* __restrict__ cursor, int* __restrict__ srcP,
                               int* __restrict__ eidP, int E) {
    int e = blockIdx.x * blockDim.x + threadIdx.x;
    if (e < E) {
        int d = dst[e];
        int p = atomicAdd(&cursor[d], 1);
        srcP[p] = src[e];
        eidP[p] = e;
    }
}

// ---------------- easum[n][k] = sum over in-edges of edge_attr[e][k] -----------------
__global__ __launch_bounds__(256) void easum_kernel(const float* __restrict__ edge_attr,
                                                    const int* __restrict__ eidP,
                                                    const int* __restrict__ row_start,
                                                    float* __restrict__ easum, int N) {
    int t = threadIdx.x;
    int node = blockIdx.x * 16 + (t >> 4);
    int k = t & 15;
    if (node >= N) return;
    int rs = row_start[node], re = row_start[node + 1];
    float acc = 0.f;
    for (int p = rs; p < re; ++p)
        acc += edge_attr[(size_t)eidP[p] * 16 + k];
    easum[node * 16 + k] = acc;
}

// ---------------- x = h + sum_in h[src] + easum@We + deg*be --------------------------
__global__ __launch_bounds__(256) void aggregate_kernel(
    const float* __restrict__ h, const int* __restrict__ srcP,
    const int* __restrict__ row_start, const float* __restrict__ easum,
    const float* __restrict__ We, const float* __restrict__ be,
    float* __restrict__ x, int N) {
    __shared__ float2 WeL[16 * 64];
    int t = threadIdx.x;
    const float2* Wg2 = (const float2*)We;
    for (int i = t; i < 16 * 64; i += 256) WeL[i] = Wg2[i];
    __syncthreads();

    int wave = t >> 6, lane = t & 63;
    int n = blockIdx.x * 4 + wave;
    if (n >= N) return;
    const float2* h2 = (const float2*)h;
    float2 acc = h2[(size_t)n * 64 + lane];   // self term
    float2 acc2 = make_float2(0.f, 0.f);
    int rs = row_start[n], re = row_start[n + 1];
    float myea = (lane < 16) ? easum[n * 16 + lane] : 0.f;

    for (int base = rs; base < re; base += 64) {
        int cnt = min(64, re - base);
        int myS = (base + lane < re) ? srcP[base + lane] : 0;
        int j = 0;
        for (; j + 7 < cnt; j += 8) {
            int s0 = __shfl(myS, j);
            int s1 = __shfl(myS, j + 1);
            int s2 = __shfl(myS, j + 2);
            int s3 = __shfl(myS, j + 3);
            int s4 = __shfl(myS, j + 4);
            int s5 = __shfl(myS, j + 5);
            int s6 = __shfl(myS, j + 6);
            int s7 = __shfl(myS, j + 7);
            float2 a0 = h2[(size_t)s0 * 64 + lane];
            float2 a1 = h2[(size_t)s1 * 64 + lane];
            float2 a2 = h2[(size_t)s2 * 64 + lane];
            float2 a3 = h2[(size_t)s3 * 64 + lane];
            float2 a4 = h2[(size_t)s4 * 64 + lane];
            float2 a5 = h2[(size_t)s5 * 64 + lane];
            float2 a6 = h2[(size_t)s6 * 64 + lane];
            float2 a7 = h2[(size_t)s7 * 64 + lane];
            acc.x += (a0.x + a1.x) + (a2.x + a3.x);
            acc.y += (a0.y + a1.y) + (a2.y + a3.y);
            acc2.x += (a4.x + a5.x) + (a6.x + a7.x);
            acc2.y += (a4.y + a5.y) + (a6.y + a7.y);
        }
        for (; j + 3 < cnt; j += 4) {
            int s0 = __shfl(myS, j);
            int s1 = __shfl(myS, j + 1);
            int s2 = __shfl(myS, j + 2);
            int s3 = __shfl(myS, j + 3);
            float2 a0 = h2[(size_t)s0 * 64 + lane];
            float2 a1 = h2[(size_t)s1 * 64 + lane];
            float2 a2 = h2[(size_t)s2 * 64 + lane];
            float2 a3 = h2[(size_t)s3 * 64 + lane];
            acc.x += (a0.x + a1.x) + (a2.x + a3.x);
            acc.y += (a0.y + a1.y) + (a2.y + a3.y);
        }
        for (; j < cnt; ++j) {
            int s = __shfl(myS, j);
            float2 a = h2[(size_t)s * 64 + lane];
            acc.x += a.x;
            acc.y += a.y;
        }
    }
    acc.x += acc2.x;
    acc.y += acc2.y;

    float degf = (float)(re - rs);
    float2 be2 = ((const float2*)be)[lane];
#pragma unroll
    for (int k = 0; k < 16; ++k) {
        float e = __shfl(myea, k);
        float2 w = WeL[k * 64 + lane];
        acc.x = fmaf(e, w.x, acc.x);
        acc.y = fmaf(e, w.y, acc.y);
    }
    acc.x += degf * be2.x;
    acc.y += degf * be2.y;
    ((float2*)x)[(size_t)n * 64 + lane] = acc;
}

// ---------------- GEMM: Z = X @ W + b  (X: N x 128, W: 128 x 128) ---------------------
__global__ __launch_bounds__(256) void gemm128_kernel(
    const float* __restrict__ X, const float* __restrict__ W, const float* __restrict__ b,
    float* __restrict__ Z, int N, float* __restrict__ bnsum, float* __restrict__ bnsumsq) {
    __shared__ float Wl[64 * NH];   // half of W (32KB)
    __shared__ float Xl[32 * NH];   // X tile (16KB)
    int t = threadIdx.x;
    int row0 = blockIdx.x * 32;

    const float4* Xg4 = (const float4*)X;
    float4* Xl4 = (float4*)Xl;
    for (int i = t; i < 32 * 32; i += 256) {
        int r = i >> 5;
        int gr = row0 + r;
        Xl4[i] = (gr < N) ? Xg4[(size_t)gr * 32 + (i & 31)] : make_float4(0.f, 0.f, 0.f, 0.f);
    }

    int tcol = t & 31, trow = t >> 5;
    float4 bias = ((const float4*)b)[tcol];
    float4 acc[4];
#pragma unroll
    for (int i = 0; i < 4; ++i) acc[i] = bias;

    float4* Wl4 = (float4*)Wl;
    const float4* Wg4 = (const float4*)W;
    for (int half = 0; half < 2; ++half) {
        __syncthreads();
        for (int i = t; i < 64 * 32; i += 256) Wl4[i] = Wg4[half * 64 * 32 + i];
        __syncthreads();
#pragma unroll 4
        for (int k4 = 0; k4 < 16; ++k4) {
            float4 w0 = Wl4[(k4 * 4 + 0) * 32 + tcol];
            float4 w1 = Wl4[(k4 * 4 + 1) * 32 + tcol];
            float4 w2 = Wl4[(k4 * 4 + 2) * 32 + tcol];
            float4 w3 = Wl4[(k4 * 4 + 3) * 32 + tcol];
#pragma unroll
            for (int i = 0; i < 4; ++i) {
                float4 a = Xl4[(trow * 4 + i) * 32 + half * 16 + k4];
                acc[i].x = fmaf(a.x, w0.x, fmaf(a.y, w1.x, fmaf(a.z, w2.x, fmaf(a.w, w3.x, acc[i].x))));
                acc[i].y = fmaf(a.x, w0.y, fmaf(a.y, w1.y, fmaf(a.z, w2.y, fmaf(a.w, w3.y, acc[i].y))));
                acc[i].z = fmaf(a.x, w0.z, fmaf(a.y, w1.z, fmaf(a.z, w2.z, fmaf(a.w, w3.z, acc[i].z))));
                acc[i].w = fmaf(a.x, w0.w, fmaf(a.y, w1.w, fmaf(a.z, w2.w, fmaf(a.w, w3.w, acc[i].w))));
            }
        }
    }

#pragma unroll
    for (int i = 0; i < 4; ++i) {
        int gr = row0 + trow * 4 + i;
        if (gr < N) ((float4*)Z)[(size_t)gr * 32 + tcol] = acc[i];
    }

    if (bnsum) {
        float4 s = make_float4(0.f, 0.f, 0.f, 0.f), q = make_float4(0.f, 0.f, 0.f, 0.f);
#pragma unroll
        for (int i = 0; i < 4; ++i) {
            int gr = row0 + trow * 4 + i;
            if (gr < N) {
                s.x += acc[i].x; s.y += acc[i].y; s.z += acc[i].z; s.w += acc[i].w;
                q.x += acc[i].x * acc[i].x; q.y += acc[i].y * acc[i].y;
                q.z += acc[i].z * acc[i].z; q.w += acc[i].w * acc[i].w;
            }
        }
        __syncthreads();
        ((float4*)Xl)[trow * 32 + tcol] = s;
        ((float4*)(Xl + 8 * NH))[trow * 32 + tcol] = q;
        __syncthreads();
        if (t < NH) {
            float ss = 0.f, qq = 0.f;
#pragma unroll
            for (int r = 0; r < 8; ++r) {
                ss += Xl[r * NH + t];
                qq += Xl[8 * NH + r * NH + t];
            }
            atomicAdd(&bnsum[t], ss);
            atomicAdd(&bnsumsq[t], qq);
        }
    }
}

// ---------------- BN finalize ---------------------------------------------------------
__global__ void bnfinal_kernel(const float* __restrict__ bnsum, const float* __restrict__ bnsumsq,
                               const float* __restrict__ gamma, const float* __restrict__ beta,
                               float* __restrict__ scale, float* __restrict__ shift, float invN) {
    int c = threadIdx.x;
    float mu = bnsum[c] * invN;
    float var = bnsumsq[c] * invN - mu * mu;
    float sc = gamma[c] * rsqrtf(var + 1e-5f);
    scale[c] = sc;
    shift[c] = beta[c] - mu * sc;
}

// ---------------- h = relu(z*scale+shift) + h ----------------------------------------
__global__ __launch_bounds__(256) void update_kernel(
    const float* __restrict__ z, float* __restrict__ h,
    const float* __restrict__ scale, const float* __restrict__ shift, int total4) {
    int idx = blockIdx.x * 256 + threadIdx.x;
    if (idx >= total4) return;
    int q = idx & 31;
    float4 zv = ((const float4*)z)[idx];
    float4 sc = ((const float4*)scale)[q];
    float4 sh = ((const float4*)shift)[q];
    float4 hv = ((const float4*)h)[idx];
    float4 r;
    r.x = fmaxf(fmaf(zv.x, sc.x, sh.x), 0.f) + hv.x;
    r.y = fmaxf(fmaf(zv.y, sc.y, sh.y), 0.f) + hv.y;
    r.z = fmaxf(fmaf(zv.z, sc.z, sh.z), 0.f) + hv.z;
    r.w = fmaxf(fmaf(zv.w, sc.w, sh.w), 0.f) + hv.w;
    ((float4*)h)[idx] = r;
}

// ---------------- pool: block per graph, sorted batch -> no atomics ------------------
__global__ __launch_bounds__(256) void pool_kernel(
    const float* __restrict__ h, const int* __restrict__ gstart,
    float* __restrict__ pooled, int G) {
    int g = blockIdx.x;
    int t = threadIdx.x;
    int s = gstart[g], e = gstart[g + 1];
    int c = t & 127, half = t >> 7;
    float acc = 0.f;
    for (int n = s + half; n < e; n += 2)
        acc += h[(size_t)n * NH + c];
    __shared__ float red[256];
    red[t] = acc;
    __syncthreads();
    if (t < NH) pooled[(size_t)g * NH + t] = red[t] + red[t + NH];
}

// ---------------- JK head -------------------------------------------------------------
__global__ void jk_kernel(const float* __restrict__ pooled, const float* __restrict__ jkW,
                          const float* __restrict__ jkb, float* __restrict__ out, int G) {
    int idx = blockIdx.x * blockDim.x + threadIdx.x;
    if (idx >= G * 10) return;
    int g = idx / 10, c = idx % 10;
    float acc = 0.f;
    for (int l = 0; l < LAYERS + 1; ++l) {
        acc += jkb[l * 10 + c];
        const float* pg = pooled + ((size_t)l * G + g) * NH;
        const float* wl = jkW + (size_t)l * NH * 10 + c;
        float s = 0.f;
#pragma unroll 16
        for (int k = 0; k < NH; ++k) s = fmaf(pg[k], wl[k * 10], s);
        acc += s;
    }
    out[idx] = acc;
}

extern "C" void kernel_launch(void* const* d_in, const int* in_sizes, int n_in,
                              void* d_out, int out_size, void* d_ws, size_t ws_size,
                              hipStream_t stream) {
    const float* h_in      = (const float*)d_in[0];
    const float* edge_attr = (const float*)d_in[1];
    const int*   edge_idx  = (const int*)d_in[2];
    const int*   batch     = (const int*)d_in[5];
    const float* emb_W     = (const float*)d_in[6];
    const float* emb_b     = (const float*)d_in[7];
    const float* conv_W    = (const float*)d_in[8];
    const float* conv_b    = (const float*)d_in[9];
    const float* conv_We   = (const float*)d_in[10];
    const float* conv_be   = (const float*)d_in[11];
    const float* bn_gamma  = (const float*)d_in[12];
    const float* bn_beta   = (const float*)d_in[13];
    const float* jk_W      = (const float*)d_in[14];
    const float* jk_b      = (const float*)d_in[15];
    float* out = (float*)d_out;

    const int N = in_sizes[0] / NH;
    const int E = in_sizes[1] / 16;
    const int G = out_size / 10;
    const int NB = (N + 1023) / 1024;   // scan blocks

    const int* src = edge_idx;
    const int* dst = edge_idx + E;

    size_t off = 0;
    auto alloc = [&](size_t bytes) -> void* {
        void* p = (char*)d_ws + off;
        off += (bytes + 255) & ~(size_t)255;
        return p;
    };
    float* hbuf = (float*)alloc((size_t)N * NH * 4);
    float* xbuf = (float*)alloc((size_t)N * NH * 4);
    float* zbuf = (float*)alloc((size_t)N * NH * 4);
    float* pooled  = (float*)alloc((size_t)(LAYERS + 1) * G * NH * 4);
    float* easum   = (float*)alloc((size_t)N * 16 * 4);
    size_t zero_off = off;
    float* bnsum   = (float*)alloc((size_t)LAYERS * NH * 4);
    float* bnsumsq = (float*)alloc((size_t)LAYERS * NH * 4);
    int* deg       = (int*)alloc((size_t)N * 4);
    size_t zero_bytes = off - zero_off;
    float* scale   = (float*)alloc(NH * 4);
    float* shift   = (float*)alloc(NH * 4);
    int* row_start = (int*)alloc((size_t)(N + 1) * 4);
    int* cursor    = (int*)alloc((size_t)N * 4);
    int* gstart    = (int*)alloc((size_t)(G + 1) * 4);
    int* bsum      = (int*)alloc((size_t)NB * 4);
    int* srcP      = (int*)alloc((size_t)E * 4);
    int* eidP      = (int*)alloc((size_t)E * 4);
    (void)ws_size; (void)n_in;

    hipMemsetAsync((char*)d_ws + zero_off, 0, zero_bytes, stream);

    // CSR by dst (hierarchical scan) + graph starts from sorted batch
    hist_kernel<<<(E + 255) / 256, 256, 0, stream>>>(dst, deg, E);
    gstart_kernel<<<(N + 255) / 256, 256, 0, stream>>>(batch, gstart, N, G);
    block_sum_kernel<<<NB, 256, 0, stream>>>(deg, bsum, N);
    scan_partials_kernel<<<1, 1024, 0, stream>>>(bsum, NB, row_start, N);
    local_scan_kernel<<<NB, 256, 0, stream>>>(deg, bsum, row_start, cursor, N);
    scatter_kernel<<<(E + 255) / 256, 256, 0, stream>>>(src, dst, cursor, srcP, eidP, E);
    easum_kernel<<<(N + 15) / 16, 256, 0, stream>>>(edge_attr, eidP, row_start, easum, N);

    dim3 gemm_grid((N + 31) / 32);
    dim3 agg_grid((N + 3) / 4);
    dim3 ew_grid((N * 32 + 255) / 256);

    gemm128_kernel<<<gemm_grid, 256, 0, stream>>>(h_in, emb_W, emb_b, hbuf, N, nullptr, nullptr);
    pool_kernel<<<G, 256, 0, stream>>>(hbuf, gstart, pooled, G);

    for (int l = 0; l < LAYERS; ++l) {
        aggregate_kernel<<<agg_grid, 256, 0, stream>>>(
            hbuf, srcP, row_start, easum,
            conv_We + (size_t)l * 16 * NH, conv_be + (size_t)l * NH, xbuf, N);
        gemm128_kernel<<<gemm_grid, 256, 0, stream>>>(
            xbuf, conv_W + (size_t)l * NH * NH, conv_b + (size_t)l * NH, zbuf, N,
            bnsum + (size_t)l * NH, bnsumsq + (size_t)l * NH);
        bnfinal_kernel<<<1, NH, 0, stream>>>(
            bnsum + (size_t)l * NH, bnsumsq + (size_t)l * NH,
            bn_gamma + (size_t)l * NH, bn_beta + (size_t)l * NH,
            scale, shift, 1.0f / (float)N);
        update_kernel<<<ew_grid, 256, 0, stream>>>(zbuf, hbuf, scale, shift, N * 32);
        pool_kernel<<<G, 256, 0, stream>>>(hbuf, gstart, pooled + (size_t)(l + 1) * G * NH, G);
    }

    jk_kernel<<<(G * 10 + 255) / 256, 256, 0, stream>>>(pooled, jk_W, jk_b, out, G);
}

// Round 4
// 843.194 us; speedup vs baseline: 2.1914x; 1.1150x over previous
//
#include <hip/hip_runtime.h>

#define NH 128
#define LAYERS 4

// ---------------- histogram (edge dst degrees) ----------------
__global__ void hist_kernel(const int* __restrict__ idx, int* __restrict__ cnt, int n) {
    int i = blockIdx.x * blockDim.x + threadIdx.x;
    if (i < n) atomicAdd(&cnt[idx[i]], 1);
}

// ---------------- gstart from sorted batch: boundary detection ----------------
__global__ void gstart_kernel(const int* __restrict__ batch, int* __restrict__ gstart,
                              int N, int G) {
    int i = blockIdx.x * blockDim.x + threadIdx.x;
    if (i >= N) return;
    int b = batch[i];
    int prev = (i == 0) ? -1 : batch[i - 1];
    for (int g = prev + 1; g <= b; ++g) gstart[g] = i;
    if (i == N - 1)
        for (int g = b + 1; g <= G; ++g) gstart[g] = N;
}

// ---------------- hierarchical scan: phase A ----------------
__global__ __launch_bounds__(256) void block_sum_kernel(const int* __restrict__ deg,
                                                        int* __restrict__ bsum, int n) {
    __shared__ int red[256];
    int t = threadIdx.x;
    int base = blockIdx.x * 1024;
    int s = 0;
#pragma unroll
    for (int i = 0; i < 4; ++i) {
        int idx = base + i * 256 + t;
        if (idx < n) s += deg[idx];
    }
    red[t] = s;
    __syncthreads();
    for (int off = 128; off > 0; off >>= 1) {
        if (t < off) red[t] += red[t + off];
        __syncthreads();
    }
    if (t == 0) bsum[blockIdx.x] = red[0];
}

// ---------------- phase B ----------------
__global__ __launch_bounds__(1024) void scan_partials_kernel(int* __restrict__ bsum, int nb,
                                                             int* __restrict__ row_start, int n) {
    __shared__ int part[1024];
    int t = threadIdx.x;
    int v = (t < nb) ? bsum[t] : 0;
    part[t] = v;
    __syncthreads();
    for (int off = 1; off < 1024; off <<= 1) {
        int u = (t >= off) ? part[t - off] : 0;
        __syncthreads();
        part[t] += u;
        __syncthreads();
    }
    if (t < nb) bsum[t] = part[t] - v;
    if (t == 1023) row_start[n] = part[1023];
}

// ---------------- phase C ----------------
__global__ __launch_bounds__(256) void local_scan_kernel(const int* __restrict__ deg,
                                                         const int* __restrict__ bsum,
                                                         int* __restrict__ row_start,
                                                         int* __restrict__ cursor, int n) {
    __shared__ int part[256];
    int t = threadIdx.x;
    int base = blockIdx.x * 1024 + t * 4;
    int v0 = 0, v1 = 0, v2 = 0, v3 = 0;
    if (base + 3 < n) {
        int4 v = *(const int4*)(deg + base);
        v0 = v.x; v1 = v.y; v2 = v.z; v3 = v.w;
    } else {
        if (base + 0 < n) v0 = deg[base + 0];
        if (base + 1 < n) v1 = deg[base + 1];
        if (base + 2 < n) v2 = deg[base + 2];
        if (base + 3 < n) v3 = deg[base + 3];
    }
    int tsum = v0 + v1 + v2 + v3;
    part[t] = tsum;
    __syncthreads();
    for (int off = 1; off < 256; off <<= 1) {
        int u = (t >= off) ? part[t - off] : 0;
        __syncthreads();
        part[t] += u;
        __syncthreads();
    }
    int run = bsum[blockIdx.x] + part[t] - tsum;
    int r0 = run, r1 = run + v0, r2 = r1 + v1, r3 = r2 + v2;
    if (base + 3 < n) {
        *(int4*)(row_start + base) = make_int4(r0, r1, r2, r3);
        *(int4*)(cursor + base) = make_int4(r0, r1, r2, r3);
    } else {
        if (base + 0 < n) { row_start[base + 0] = r0; cursor[base + 0] = r0; }
        if (base + 1 < n) { row_start[base + 1] = r1; cursor[base + 1] = r1; }
        if (base + 2 < n) { row_start[base + 2] = r2; cursor[base + 2] = r2; }
        if (base + 3 < n) { row_start[base + 3] = r3; cursor[base + 3] = r3; }
    }
}

__global__ void scatter_kernel(const int* __restrict__ src, const int* __restrict__ dst,
                               int* __restrict__ cursor, int* __restrict__ srcP,
                               int* __restrict__ eidP, int E) {
    int e = blockIdx.x * blockDim.x + threadIdx.x;
    if (e < E) {
        int d = dst[e];
        int p = atomicAdd(&cursor[d], 1);
        srcP[p] = src[e];
        eidP[p] = e;
    }
}

// ---------------- easum ----------------
__global__ __launch_bounds__(256) void easum_kernel(const float* __restrict__ edge_attr,
                                                    const int* __restrict__ eidP,
                                                    const int* __restrict__ row_start,
                                                    float* __restrict__ easum, int N) {
    int t = threadIdx.x;
    int node = blockIdx.x * 16 + (t >> 4);
    int k = t & 15;
    if (node >= N) return;
    int rs = row_start[node], re = row_start[node + 1];
    float acc = 0.f;
    for (int p = rs; p < re; ++p)
        acc += edge_attr[(size_t)eidP[p] * 16 + k];
    easum[node * 16 + k] = acc;
}

// ---------------- aggregate: x = h + sum_in h[src] + easum@We + deg*be ---------------
__global__ __launch_bounds__(256) void aggregate_kernel(
    const float* __restrict__ h, const int* __restrict__ srcP,
    const int* __restrict__ row_start, const float* __restrict__ easum,
    const float* __restrict__ We, const float* __restrict__ be,
    float* __restrict__ x, int N) {
    __shared__ float2 WeL[16 * 64];
    int t = threadIdx.x;
    const float2* Wg2 = (const float2*)We;
    for (int i = t; i < 16 * 64; i += 256) WeL[i] = Wg2[i];
    __syncthreads();

    int wave = t >> 6, lane = t & 63;
    int n = blockIdx.x * 4 + wave;
    if (n >= N) return;
    const float2* h2 = (const float2*)h;
    float2 acc = h2[(size_t)n * 64 + lane];
    float2 acc2 = make_float2(0.f, 0.f);
    float2 acc3 = make_float2(0.f, 0.f);
    float2 acc4 = make_float2(0.f, 0.f);
    int rs = row_start[n], re = row_start[n + 1];
    float myea = (lane < 16) ? easum[n * 16 + lane] : 0.f;

    for (int base = rs; base < re; base += 64) {
        int cnt = min(64, re - base);
        int myS = (base + lane < re) ? srcP[base + lane] : 0;
        int j = 0;
        for (; j + 15 < cnt; j += 16) {
            int s0 = __shfl(myS, j);      int s1 = __shfl(myS, j + 1);
            int s2 = __shfl(myS, j + 2);  int s3 = __shfl(myS, j + 3);
            int s4 = __shfl(myS, j + 4);  int s5 = __shfl(myS, j + 5);
            int s6 = __shfl(myS, j + 6);  int s7 = __shfl(myS, j + 7);
            int s8 = __shfl(myS, j + 8);  int s9 = __shfl(myS, j + 9);
            int sa = __shfl(myS, j + 10); int sb = __shfl(myS, j + 11);
            int sc = __shfl(myS, j + 12); int sd = __shfl(myS, j + 13);
            int se = __shfl(myS, j + 14); int sf = __shfl(myS, j + 15);
            float2 a0 = h2[(size_t)s0 * 64 + lane];
            float2 a1 = h2[(size_t)s1 * 64 + lane];
            float2 a2 = h2[(size_t)s2 * 64 + lane];
            float2 a3 = h2[(size_t)s3 * 64 + lane];
            float2 a4 = h2[(size_t)s4 * 64 + lane];
            float2 a5 = h2[(size_t)s5 * 64 + lane];
            float2 a6 = h2[(size_t)s6 * 64 + lane];
            float2 a7 = h2[(size_t)s7 * 64 + lane];
            float2 a8 = h2[(size_t)s8 * 64 + lane];
            float2 a9 = h2[(size_t)s9 * 64 + lane];
            float2 aa = h2[(size_t)sa * 64 + lane];
            float2 ab = h2[(size_t)sb * 64 + lane];
            float2 ac = h2[(size_t)sc * 64 + lane];
            float2 ad = h2[(size_t)sd * 64 + lane];
            float2 ae = h2[(size_t)se * 64 + lane];
            float2 af = h2[(size_t)sf * 64 + lane];
            acc.x += (a0.x + a1.x) + (a2.x + a3.x);
            acc.y += (a0.y + a1.y) + (a2.y + a3.y);
            acc2.x += (a4.x + a5.x) + (a6.x + a7.x);
            acc2.y += (a4.y + a5.y) + (a6.y + a7.y);
            acc3.x += (a8.x + a9.x) + (aa.x + ab.x);
            acc3.y += (a8.y + a9.y) + (aa.y + ab.y);
            acc4.x += (ac.x + ad.x) + (ae.x + af.x);
            acc4.y += (ac.y + ad.y) + (ae.y + af.y);
        }
        for (; j + 3 < cnt; j += 4) {
            int s0 = __shfl(myS, j);
            int s1 = __shfl(myS, j + 1);
            int s2 = __shfl(myS, j + 2);
            int s3 = __shfl(myS, j + 3);
            float2 a0 = h2[(size_t)s0 * 64 + lane];
            float2 a1 = h2[(size_t)s1 * 64 + lane];
            float2 a2 = h2[(size_t)s2 * 64 + lane];
            float2 a3 = h2[(size_t)s3 * 64 + lane];
            acc.x += (a0.x + a1.x) + (a2.x + a3.x);
            acc.y += (a0.y + a1.y) + (a2.y + a3.y);
        }
        for (; j < cnt; ++j) {
            int s = __shfl(myS, j);
            float2 a = h2[(size_t)s * 64 + lane];
            acc.x += a.x;
            acc.y += a.y;
        }
    }
    acc.x += (acc2.x + acc3.x) + acc4.x;
    acc.y += (acc2.y + acc3.y) + acc4.y;

    float degf = (float)(re - rs);
    float2 be2 = ((const float2*)be)[lane];
#pragma unroll
    for (int k = 0; k < 16; ++k) {
        float e = __shfl(myea, k);
        float2 w = WeL[k * 64 + lane];
        acc.x = fmaf(e, w.x, acc.x);
        acc.y = fmaf(e, w.y, acc.y);
    }
    acc.x += degf * be2.x;
    acc.y += degf * be2.y;
    ((float2*)x)[(size_t)n * 64 + lane] = acc;
}

// ---------------- GEMM: Z = X @ W + b, 128-row tiles ---------------------------------
// 256 threads: tcol = t&31 (4 cols), trow = t>>5 (16 rows each). 64 acc VGPRs.
// LDS: W k-half (32KB) + X k-half tile (32KB) = 64KB. 2 blocks/CU.
__global__ __launch_bounds__(256) void gemm128_kernel(
    const float* __restrict__ X, const float* __restrict__ W, const float* __restrict__ b,
    float* __restrict__ Z, int N, float* __restrict__ bnsum, float* __restrict__ bnsumsq) {
    __shared__ float Wl[64 * NH];    // 32KB: k-half of W
    __shared__ float Xl[NH * 64];    // 32KB: 128 rows x 64 k
    int t = threadIdx.x;
    int row0 = blockIdx.x * 128;
    int tcol = t & 31, trow = t >> 5;

    float4 bias = ((const float4*)b)[tcol];
    float4 acc[16];
#pragma unroll
    for (int r = 0; r < 16; ++r) acc[r] = bias;

    float4* Wl4 = (float4*)Wl;
    float4* Xl4 = (float4*)Xl;
    const float4* Wg4 = (const float4*)W;
    const float4* Xg4 = (const float4*)X;

    for (int half = 0; half < 2; ++half) {
        __syncthreads();
        for (int i = t; i < 64 * 32; i += 256) Wl4[i] = Wg4[half * 64 * 32 + i];
        for (int i = t; i < 128 * 16; i += 256) {
            int r = i >> 4, kq = i & 15;
            int gr = row0 + r;
            Xl4[i] = (gr < N) ? Xg4[(size_t)gr * 32 + half * 16 + kq]
                              : make_float4(0.f, 0.f, 0.f, 0.f);
        }
        __syncthreads();
        for (int k4 = 0; k4 < 16; ++k4) {
            float4 w0 = Wl4[(k4 * 4 + 0) * 32 + tcol];
            float4 w1 = Wl4[(k4 * 4 + 1) * 32 + tcol];
            float4 w2 = Wl4[(k4 * 4 + 2) * 32 + tcol];
            float4 w3 = Wl4[(k4 * 4 + 3) * 32 + tcol];
#pragma unroll
            for (int r = 0; r < 16; ++r) {
                float4 a = Xl4[(trow * 16 + r) * 16 + k4];
                acc[r].x = fmaf(a.x, w0.x, fmaf(a.y, w1.x, fmaf(a.z, w2.x, fmaf(a.w, w3.x, acc[r].x))));
                acc[r].y = fmaf(a.x, w0.y, fmaf(a.y, w1.y, fmaf(a.z, w2.y, fmaf(a.w, w3.y, acc[r].y))));
                acc[r].z = fmaf(a.x, w0.z, fmaf(a.y, w1.z, fmaf(a.z, w2.z, fmaf(a.w, w3.z, acc[r].z))));
                acc[r].w = fmaf(a.x, w0.w, fmaf(a.y, w1.w, fmaf(a.z, w2.w, fmaf(a.w, w3.w, acc[r].w))));
            }
        }
    }

#pragma unroll
    for (int r = 0; r < 16; ++r) {
        int gr = row0 + trow * 16 + r;
        if (gr < N) ((float4*)Z)[(size_t)gr * 32 + tcol] = acc[r];
    }

    if (bnsum) {
        float4 s = make_float4(0.f, 0.f, 0.f, 0.f), q = make_float4(0.f, 0.f, 0.f, 0.f);
#pragma unroll
        for (int r = 0; r < 16; ++r) {
            int gr = row0 + trow * 16 + r;
            if (gr < N) {
                s.x += acc[r].x; s.y += acc[r].y; s.z += acc[r].z; s.w += acc[r].w;
                q.x += acc[r].x * acc[r].x; q.y += acc[r].y * acc[r].y;
                q.z += acc[r].z * acc[r].z; q.w += acc[r].w * acc[r].w;
            }
        }
        __syncthreads();
        ((float4*)Xl)[trow * 32 + tcol] = s;   // [8][128] col sums
        ((float4*)Wl)[trow * 32 + tcol] = q;   // [8][128] col sumsq
        __syncthreads();
        if (t < NH) {
            float ss = 0.f, qq = 0.f;
#pragma unroll
            for (int r8 = 0; r8 < 8; ++r8) {
                ss += Xl[r8 * NH + t];
                qq += Wl[r8 * NH + t];
            }
            atomicAdd(&bnsum[t], ss);
            atomicAdd(&bnsumsq[t], qq);
        }
    }
}

// ---------------- update: h = relu(z*scale+shift) + h, BN finalize fused -------------
__global__ __launch_bounds__(256) void update_kernel(
    const float* __restrict__ z, float* __restrict__ h,
    const float* __restrict__ bnsum, const float* __restrict__ bnsumsq,
    const float* __restrict__ gamma, const float* __restrict__ beta,
    float invN, int total4) {
    int idx = blockIdx.x * 256 + threadIdx.x;
    if (idx >= total4) return;
    int q = idx & 31;
    float4 s4 = ((const float4*)bnsum)[q];
    float4 q4 = ((const float4*)bnsumsq)[q];
    float4 g4 = ((const float4*)gamma)[q];
    float4 b4 = ((const float4*)beta)[q];
    float4 mu, sc, sh;
    mu.x = s4.x * invN; mu.y = s4.y * invN; mu.z = s4.z * invN; mu.w = s4.w * invN;
    sc.x = g4.x * rsqrtf(fmaf(q4.x, invN, -mu.x * mu.x) + 1e-5f);
    sc.y = g4.y * rsqrtf(fmaf(q4.y, invN, -mu.y * mu.y) + 1e-5f);
    sc.z = g4.z * rsqrtf(fmaf(q4.z, invN, -mu.z * mu.z) + 1e-5f);
    sc.w = g4.w * rsqrtf(fmaf(q4.w, invN, -mu.w * mu.w) + 1e-5f);
    sh.x = b4.x - mu.x * sc.x; sh.y = b4.y - mu.y * sc.y;
    sh.z = b4.z - mu.z * sc.z; sh.w = b4.w - mu.w * sc.w;
    float4 zv = ((const float4*)z)[idx];
    float4 hv = ((const float4*)h)[idx];
    float4 r;
    r.x = fmaxf(fmaf(zv.x, sc.x, sh.x), 0.f) + hv.x;
    r.y = fmaxf(fmaf(zv.y, sc.y, sh.y), 0.f) + hv.y;
    r.z = fmaxf(fmaf(zv.z, sc.z, sh.z), 0.f) + hv.z;
    r.w = fmaxf(fmaf(zv.w, sc.w, sh.w), 0.f) + hv.w;
    ((float4*)h)[idx] = r;
}

// ---------------- pool ----------------
__global__ __launch_bounds__(256) void pool_kernel(
    const float* __restrict__ h, const int* __restrict__ gstart,
    float* __restrict__ pooled, int G) {
    int g = blockIdx.x;
    int t = threadIdx.x;
    int s = gstart[g], e = gstart[g + 1];
    int c = t & 127, half = t >> 7;
    float acc = 0.f;
    for (int n = s + half; n < e; n += 2)
        acc += h[(size_t)n * NH + c];
    __shared__ float red[256];
    red[t] = acc;
    __syncthreads();
    if (t < NH) pooled[(size_t)g * NH + t] = red[t] + red[t + NH];
}

// ---------------- JK head ----------------
__global__ void jk_kernel(const float* __restrict__ pooled, const float* __restrict__ jkW,
                          const float* __restrict__ jkb, float* __restrict__ out, int G) {
    int idx = blockIdx.x * blockDim.x + threadIdx.x;
    if (idx >= G * 10) return;
    int g = idx / 10, c = idx % 10;
    float acc = 0.f;
    for (int l = 0; l < LAYERS + 1; ++l) {
        acc += jkb[l * 10 + c];
        const float* pg = pooled + ((size_t)l * G + g) * NH;
        const float* wl = jkW + (size_t)l * NH * 10 + c;
        float s = 0.f;
#pragma unroll 16
        for (int k = 0; k < NH; ++k) s = fmaf(pg[k], wl[k * 10], s);
        acc += s;
    }
    out[idx] = acc;
}

extern "C" void kernel_launch(void* const* d_in, const int* in_sizes, int n_in,
                              void* d_out, int out_size, void* d_ws, size_t ws_size,
                              hipStream_t stream) {
    const float* h_in      = (const float*)d_in[0];
    const float* edge_attr = (const float*)d_in[1];
    const int*   edge_idx  = (const int*)d_in[2];
    const int*   batch     = (const int*)d_in[5];
    const float* emb_W     = (const float*)d_in[6];
    const float* emb_b     = (const float*)d_in[7];
    const float* conv_W    = (const float*)d_in[8];
    const float* conv_b    = (const float*)d_in[9];
    const float* conv_We   = (const float*)d_in[10];
    const float* conv_be   = (const float*)d_in[11];
    const float* bn_gamma  = (const float*)d_in[12];
    const float* bn_beta   = (const float*)d_in[13];
    const float* jk_W      = (const float*)d_in[14];
    const float* jk_b      = (const float*)d_in[15];
    float* out = (float*)d_out;

    const int N = in_sizes[0] / NH;
    const int E = in_sizes[1] / 16;
    const int G = out_size / 10;
    const int NB = (N + 1023) / 1024;

    const int* src = edge_idx;
    const int* dst = edge_idx + E;

    size_t off = 0;
    auto alloc = [&](size_t bytes) -> void* {
        void* p = (char*)d_ws + off;
        off += (bytes + 255) & ~(size_t)255;
        return p;
    };
    float* hbuf = (float*)alloc((size_t)N * NH * 4);
    float* xbuf = (float*)alloc((size_t)N * NH * 4);
    float* zbuf = (float*)alloc((size_t)N * NH * 4);
    float* pooled  = (float*)alloc((size_t)(LAYERS + 1) * G * NH * 4);
    float* easum   = (float*)alloc((size_t)N * 16 * 4);
    size_t zero_off = off;
    float* bnsum   = (float*)alloc((size_t)LAYERS * NH * 4);
    float* bnsumsq = (float*)alloc((size_t)LAYERS * NH * 4);
    int* deg       = (int*)alloc((size_t)N * 4);
    size_t zero_bytes = off - zero_off;
    int* row_start = (int*)alloc((size_t)(N + 1) * 4);
    int* cursor    = (int*)alloc((size_t)N * 4);
    int* gstart    = (int*)alloc((size_t)(G + 1) * 4);
    int* bsum      = (int*)alloc((size_t)NB * 4);
    int* srcP      = (int*)alloc((size_t)E * 4);
    int* eidP      = (int*)alloc((size_t)E * 4);
    (void)ws_size; (void)n_in;

    hipMemsetAsync((char*)d_ws + zero_off, 0, zero_bytes, stream);

    hist_kernel<<<(E + 255) / 256, 256, 0, stream>>>(dst, deg, E);
    gstart_kernel<<<(N + 255) / 256, 256, 0, stream>>>(batch, gstart, N, G);
    block_sum_kernel<<<NB, 256, 0, stream>>>(deg, bsum, N);
    scan_partials_kernel<<<1, 1024, 0, stream>>>(bsum, NB, row_start, N);
    local_scan_kernel<<<NB, 256, 0, stream>>>(deg, bsum, row_start, cursor, N);
    scatter_kernel<<<(E + 255) / 256, 256, 0, stream>>>(src, dst, cursor, srcP, eidP, E);
    easum_kernel<<<(N + 15) / 16, 256, 0, stream>>>(edge_attr, eidP, row_start, easum, N);

    dim3 gemm_grid((N + 127) / 128);
    dim3 agg_grid((N + 3) / 4);
    dim3 ew_grid((N * 32 + 255) / 256);

    gemm128_kernel<<<gemm_grid, 256, 0, stream>>>(h_in, emb_W, emb_b, hbuf, N, nullptr, nullptr);
    pool_kernel<<<G, 256, 0, stream>>>(hbuf, gstart, pooled, G);

    for (int l = 0; l < LAYERS; ++l) {
        aggregate_kernel<<<agg_grid, 256, 0, stream>>>(
            hbuf, srcP, row_start, easum,
            conv_We + (size_t)l * 16 * NH, conv_be + (size_t)l * NH, xbuf, N);
        gemm128_kernel<<<gemm_grid, 256, 0, stream>>>(
            xbuf, conv_W + (size_t)l * NH * NH, conv_b + (size_t)l * NH, zbuf, N,
            bnsum + (size_t)l * NH, bnsumsq + (size_t)l * NH);
        update_kernel<<<ew_grid, 256, 0, stream>>>(
            zbuf, hbuf, bnsum + (size_t)l * NH, bnsumsq + (size_t)l * NH,
            bn_gamma + (size_t)l * NH, bn_beta + (size_t)l * NH,
            1.0f / (float)N, N * 32);
        pool_kernel<<<G, 256, 0, stream>>>(hbuf, gstart, pooled + (size_t)(l + 1) * G * NH, G);
    }

    jk_kernel<<<(G * 10 + 255) / 256, 256, 0, stream>>>(pooled, jk_W, jk_b, out, G);
}

// Round 5
// 750.442 us; speedup vs baseline: 2.4622x; 1.1236x over previous
//
#include <hip/hip_runtime.h>

#define NH 128
#define LAYERS 4

__device__ __forceinline__ unsigned short f2bf(float f) {
    unsigned u = __float_as_uint(f);
    u += 0x7fffu + ((u >> 16) & 1u);          // round-to-nearest-even
    return (unsigned short)(u >> 16);
}

// ---------------- histogram (edge dst degrees) ----------------
__global__ void hist_kernel(const int* __restrict__ idx, int* __restrict__ cnt, int n) {
    int i = blockIdx.x * blockDim.x + threadIdx.x;
    if (i < n) atomicAdd(&cnt[idx[i]], 1);
}

// ---------------- gstart from sorted batch ----------------
__global__ void gstart_kernel(const int* __restrict__ batch, int* __restrict__ gstart,
                              int N, int G) {
    int i = blockIdx.x * blockDim.x + threadIdx.x;
    if (i >= N) return;
    int b = batch[i];
    int prev = (i == 0) ? -1 : batch[i - 1];
    for (int g = prev + 1; g <= b; ++g) gstart[g] = i;
    if (i == N - 1)
        for (int g = b + 1; g <= G; ++g) gstart[g] = N;
}

// ---------------- hierarchical scan ----------------
__global__ __launch_bounds__(256) void block_sum_kernel(const int* __restrict__ deg,
                                                        int* __restrict__ bsum, int n) {
    __shared__ int red[256];
    int t = threadIdx.x;
    int base = blockIdx.x * 1024;
    int s = 0;
#pragma unroll
    for (int i = 0; i < 4; ++i) {
        int idx = base + i * 256 + t;
        if (idx < n) s += deg[idx];
    }
    red[t] = s;
    __syncthreads();
    for (int off = 128; off > 0; off >>= 1) {
        if (t < off) red[t] += red[t + off];
        __syncthreads();
    }
    if (t == 0) bsum[blockIdx.x] = red[0];
}

__global__ __launch_bounds__(1024) void scan_partials_kernel(int* __restrict__ bsum, int nb,
                                                             int* __restrict__ row_start, int n) {
    __shared__ int part[1024];
    int t = threadIdx.x;
    int v = (t < nb) ? bsum[t] : 0;
    part[t] = v;
    __syncthreads();
    for (int off = 1; off < 1024; off <<= 1) {
        int u = (t >= off) ? part[t - off] : 0;
        __syncthreads();
        part[t] += u;
        __syncthreads();
    }
    if (t < nb) bsum[t] = part[t] - v;
    if (t == 1023) row_start[n] = part[1023];
}

__global__ __launch_bounds__(256) void local_scan_kernel(const int* __restrict__ deg,
                                                         const int* __restrict__ bsum,
                                                         int* __restrict__ row_start,
                                                         int* __restrict__ cursor, int n) {
    __shared__ int part[256];
    int t = threadIdx.x;
    int base = blockIdx.x * 1024 + t * 4;
    int v0 = 0, v1 = 0, v2 = 0, v3 = 0;
    if (base + 3 < n) {
        int4 v = *(const int4*)(deg + base);
        v0 = v.x; v1 = v.y; v2 = v.z; v3 = v.w;
    } else {
        if (base + 0 < n) v0 = deg[base + 0];
        if (base + 1 < n) v1 = deg[base + 1];
        if (base + 2 < n) v2 = deg[base + 2];
        if (base + 3 < n) v3 = deg[base + 3];
    }
    int tsum = v0 + v1 + v2 + v3;
    part[t] = tsum;
    __syncthreads();
    for (int off = 1; off < 256; off <<= 1) {
        int u = (t >= off) ? part[t - off] : 0;
        __syncthreads();
        part[t] += u;
        __syncthreads();
    }
    int run = bsum[blockIdx.x] + part[t] - tsum;
    int r0 = run, r1 = run + v0, r2 = r1 + v1, r3 = r2 + v2;
    if (base + 3 < n) {
        *(int4*)(row_start + base) = make_int4(r0, r1, r2, r3);
        *(int4*)(cursor + base) = make_int4(r0, r1, r2, r3);
    } else {
        if (base + 0 < n) { row_start[base + 0] = r0; cursor[base + 0] = r0; }
        if (base + 1 < n) { row_start[base + 1] = r1; cursor[base + 1] = r1; }
        if (base + 2 < n) { row_start[base + 2] = r2; cursor[base + 2] = r2; }
        if (base + 3 < n) { row_start[base + 3] = r3; cursor[base + 3] = r3; }
    }
}

__global__ void scatter_kernel(const int* __restrict__ src, const int* __restrict__ dst,
                               int* __restrict__ cursor, int* __restrict__ srcP,
                               int* __restrict__ eidP, int E) {
    int e = blockIdx.x * blockDim.x + threadIdx.x;
    if (e < E) {
        int d = dst[e];
        int p = atomicAdd(&cursor[d], 1);
        srcP[p] = src[e];
        eidP[p] = e;
    }
}

// ---------------- easum ----------------
__global__ __launch_bounds__(256) void easum_kernel(const float* __restrict__ edge_attr,
                                                    const int* __restrict__ eidP,
                                                    const int* __restrict__ row_start,
                                                    float* __restrict__ easum, int N) {
    int t = threadIdx.x;
    int node = blockIdx.x * 16 + (t >> 4);
    int k = t & 15;
    if (node >= N) return;
    int rs = row_start[node], re = row_start[node + 1];
    float acc = 0.f;
    for (int p = rs; p < re; ++p)
        acc += edge_attr[(size_t)eidP[p] * 16 + k];
    easum[node * 16 + k] = acc;
}

// ---------------- aggregate: x = h + sum_in bf16(h[src]) + easum@We + deg*be ---------
// gather from hbf (bf16): one dword (2 channels) per lane per edge
__global__ __launch_bounds__(256) void aggregate_kernel(
    const float* __restrict__ h, const unsigned* __restrict__ hbfu,
    const int* __restrict__ srcP, const int* __restrict__ row_start,
    const float* __restrict__ easum,
    const float* __restrict__ We, const float* __restrict__ be,
    float* __restrict__ x, int N) {
    __shared__ float2 WeL[16 * 64];
    int t = threadIdx.x;
    const float2* Wg2 = (const float2*)We;
    for (int i = t; i < 16 * 64; i += 256) WeL[i] = Wg2[i];
    __syncthreads();

    int wave = t >> 6, lane = t & 63;
    int n = blockIdx.x * 4 + wave;
    if (n >= N) return;
    const float2* h2 = (const float2*)h;
    float2 acc = h2[(size_t)n * 64 + lane];    // self term, fp32
    float2 acc2 = make_float2(0.f, 0.f);
    float2 acc3 = make_float2(0.f, 0.f);
    float2 acc4 = make_float2(0.f, 0.f);
    int rs = row_start[n], re = row_start[n + 1];
    float myea = (lane < 16) ? easum[n * 16 + lane] : 0.f;

    for (int base = rs; base < re; base += 64) {
        int cnt = min(64, re - base);
        int myS = (base + lane < re) ? srcP[base + lane] : 0;
        int j = 0;
        for (; j + 15 < cnt; j += 16) {
            int s0 = __shfl(myS, j);      int s1 = __shfl(myS, j + 1);
            int s2 = __shfl(myS, j + 2);  int s3 = __shfl(myS, j + 3);
            int s4 = __shfl(myS, j + 4);  int s5 = __shfl(myS, j + 5);
            int s6 = __shfl(myS, j + 6);  int s7 = __shfl(myS, j + 7);
            int s8 = __shfl(myS, j + 8);  int s9 = __shfl(myS, j + 9);
            int sa = __shfl(myS, j + 10); int sb = __shfl(myS, j + 11);
            int sc = __shfl(myS, j + 12); int sd = __shfl(myS, j + 13);
            int se = __shfl(myS, j + 14); int sf = __shfl(myS, j + 15);
            unsigned u0 = hbfu[(size_t)s0 * 64 + lane];
            unsigned u1 = hbfu[(size_t)s1 * 64 + lane];
            unsigned u2 = hbfu[(size_t)s2 * 64 + lane];
            unsigned u3 = hbfu[(size_t)s3 * 64 + lane];
            unsigned u4 = hbfu[(size_t)s4 * 64 + lane];
            unsigned u5 = hbfu[(size_t)s5 * 64 + lane];
            unsigned u6 = hbfu[(size_t)s6 * 64 + lane];
            unsigned u7 = hbfu[(size_t)s7 * 64 + lane];
            unsigned u8 = hbfu[(size_t)s8 * 64 + lane];
            unsigned u9 = hbfu[(size_t)s9 * 64 + lane];
            unsigned ua = hbfu[(size_t)sa * 64 + lane];
            unsigned ub = hbfu[(size_t)sb * 64 + lane];
            unsigned uc = hbfu[(size_t)sc * 64 + lane];
            unsigned ud = hbfu[(size_t)sd * 64 + lane];
            unsigned ue = hbfu[(size_t)se * 64 + lane];
            unsigned uf = hbfu[(size_t)sf * 64 + lane];
            acc.x  += __uint_as_float(u0 << 16) + __uint_as_float(u1 << 16)
                    + __uint_as_float(u2 << 16) + __uint_as_float(u3 << 16);
            acc.y  += __uint_as_float(u0 & 0xffff0000u) + __uint_as_float(u1 & 0xffff0000u)
                    + __uint_as_float(u2 & 0xffff0000u) + __uint_as_float(u3 & 0xffff0000u);
            acc2.x += __uint_as_float(u4 << 16) + __uint_as_float(u5 << 16)
                    + __uint_as_float(u6 << 16) + __uint_as_float(u7 << 16);
            acc2.y += __uint_as_float(u4 & 0xffff0000u) + __uint_as_float(u5 & 0xffff0000u)
                    + __uint_as_float(u6 & 0xffff0000u) + __uint_as_float(u7 & 0xffff0000u);
            acc3.x += __uint_as_float(u8 << 16) + __uint_as_float(u9 << 16)
                    + __uint_as_float(ua << 16) + __uint_as_float(ub << 16);
            acc3.y += __uint_as_float(u8 & 0xffff0000u) + __uint_as_float(u9 & 0xffff0000u)
                    + __uint_as_float(ua & 0xffff0000u) + __uint_as_float(ub & 0xffff0000u);
            acc4.x += __uint_as_float(uc << 16) + __uint_as_float(ud << 16)
                    + __uint_as_float(ue << 16) + __uint_as_float(uf << 16);
            acc4.y += __uint_as_float(uc & 0xffff0000u) + __uint_as_float(ud & 0xffff0000u)
                    + __uint_as_float(ue & 0xffff0000u) + __uint_as_float(uf & 0xffff0000u);
        }
        for (; j + 3 < cnt; j += 4) {
            int s0 = __shfl(myS, j);
            int s1 = __shfl(myS, j + 1);
            int s2 = __shfl(myS, j + 2);
            int s3 = __shfl(myS, j + 3);
            unsigned u0 = hbfu[(size_t)s0 * 64 + lane];
            unsigned u1 = hbfu[(size_t)s1 * 64 + lane];
            unsigned u2 = hbfu[(size_t)s2 * 64 + lane];
            unsigned u3 = hbfu[(size_t)s3 * 64 + lane];
            acc.x += __uint_as_float(u0 << 16) + __uint_as_float(u1 << 16)
                   + __uint_as_float(u2 << 16) + __uint_as_float(u3 << 16);
            acc.y += __uint_as_float(u0 & 0xffff0000u) + __uint_as_float(u1 & 0xffff0000u)
                   + __uint_as_float(u2 & 0xffff0000u) + __uint_as_float(u3 & 0xffff0000u);
        }
        for (; j < cnt; ++j) {
            int s = __shfl(myS, j);
            unsigned u = hbfu[(size_t)s * 64 + lane];
            acc.x += __uint_as_float(u << 16);
            acc.y += __uint_as_float(u & 0xffff0000u);
        }
    }
    acc.x += (acc2.x + acc3.x) + acc4.x;
    acc.y += (acc2.y + acc3.y) + acc4.y;

    float degf = (float)(re - rs);
    float2 be2 = ((const float2*)be)[lane];
#pragma unroll
    for (int k = 0; k < 16; ++k) {
        float e = __shfl(myea, k);
        float2 w = WeL[k * 64 + lane];
        acc.x = fmaf(e, w.x, acc.x);
        acc.y = fmaf(e, w.y, acc.y);
    }
    acc.x += degf * be2.x;
    acc.y += degf * be2.y;
    ((float2*)x)[(size_t)n * 64 + lane] = acc;
}

// ---------------- GEMM: Z = X @ W + b, 128-row tiles ---------------------------------
__global__ __launch_bounds__(256) void gemm128_kernel(
    const float* __restrict__ X, const float* __restrict__ W, const float* __restrict__ b,
    float* __restrict__ Z, int N, float* __restrict__ bnsum, float* __restrict__ bnsumsq,
    unsigned short* __restrict__ hbf) {
    __shared__ float Wl[64 * NH];
    __shared__ float Xl[NH * 64];
    int t = threadIdx.x;
    int row0 = blockIdx.x * 128;
    int tcol = t & 31, trow = t >> 5;

    float4 bias = ((const float4*)b)[tcol];
    float4 acc[16];
#pragma unroll
    for (int r = 0; r < 16; ++r) acc[r] = bias;

    float4* Wl4 = (float4*)Wl;
    float4* Xl4 = (float4*)Xl;
    const float4* Wg4 = (const float4*)W;
    const float4* Xg4 = (const float4*)X;

    for (int half = 0; half < 2; ++half) {
        __syncthreads();
        for (int i = t; i < 64 * 32; i += 256) Wl4[i] = Wg4[half * 64 * 32 + i];
        for (int i = t; i < 128 * 16; i += 256) {
            int r = i >> 4, kq = i & 15;
            int gr = row0 + r;
            Xl4[i] = (gr < N) ? Xg4[(size_t)gr * 32 + half * 16 + kq]
                              : make_float4(0.f, 0.f, 0.f, 0.f);
        }
        __syncthreads();
        for (int k4 = 0; k4 < 16; ++k4) {
            float4 w0 = Wl4[(k4 * 4 + 0) * 32 + tcol];
            float4 w1 = Wl4[(k4 * 4 + 1) * 32 + tcol];
            float4 w2 = Wl4[(k4 * 4 + 2) * 32 + tcol];
            float4 w3 = Wl4[(k4 * 4 + 3) * 32 + tcol];
#pragma unroll
            for (int r = 0; r < 16; ++r) {
                float4 a = Xl4[(trow * 16 + r) * 16 + k4];
                acc[r].x = fmaf(a.x, w0.x, fmaf(a.y, w1.x, fmaf(a.z, w2.x, fmaf(a.w, w3.x, acc[r].x))));
                acc[r].y = fmaf(a.x, w0.y, fmaf(a.y, w1.y, fmaf(a.z, w2.y, fmaf(a.w, w3.y, acc[r].y))));
                acc[r].z = fmaf(a.x, w0.z, fmaf(a.y, w1.z, fmaf(a.z, w2.z, fmaf(a.w, w3.z, acc[r].z))));
                acc[r].w = fmaf(a.x, w0.w, fmaf(a.y, w1.w, fmaf(a.z, w2.w, fmaf(a.w, w3.w, acc[r].w))));
            }
        }
    }

#pragma unroll
    for (int r = 0; r < 16; ++r) {
        int gr = row0 + trow * 16 + r;
        if (gr < N) {
            ((float4*)Z)[(size_t)gr * 32 + tcol] = acc[r];
            if (hbf)
                ((ushort4*)hbf)[(size_t)gr * 32 + tcol] =
                    make_ushort4(f2bf(acc[r].x), f2bf(acc[r].y), f2bf(acc[r].z), f2bf(acc[r].w));
        }
    }

    if (bnsum) {
        float4 s = make_float4(0.f, 0.f, 0.f, 0.f), q = make_float4(0.f, 0.f, 0.f, 0.f);
#pragma unroll
        for (int r = 0; r < 16; ++r) {
            int gr = row0 + trow * 16 + r;
            if (gr < N) {
                s.x += acc[r].x; s.y += acc[r].y; s.z += acc[r].z; s.w += acc[r].w;
                q.x += acc[r].x * acc[r].x; q.y += acc[r].y * acc[r].y;
                q.z += acc[r].z * acc[r].z; q.w += acc[r].w * acc[r].w;
            }
        }
        __syncthreads();
        ((float4*)Xl)[trow * 32 + tcol] = s;
        ((float4*)Wl)[trow * 32 + tcol] = q;
        __syncthreads();
        if (t < NH) {
            float ss = 0.f, qq = 0.f;
#pragma unroll
            for (int r8 = 0; r8 < 8; ++r8) {
                ss += Xl[r8 * NH + t];
                qq += Wl[r8 * NH + t];
            }
            atomicAdd(&bnsum[t], ss);
            atomicAdd(&bnsumsq[t], qq);
        }
    }
}

// ---------------- fused: BN finalize + h=relu(z*sc+sh)+h + hbf + pool ----------------
// block per graph (batch sorted): zero atomics, pool in registers
__global__ __launch_bounds__(256) void update_pool_kernel(
    const float* __restrict__ z, float* __restrict__ h, unsigned short* __restrict__ hbf,
    const float* __restrict__ bnsum, const float* __restrict__ bnsumsq,
    const float* __restrict__ gamma, const float* __restrict__ beta,
    float invN, const int* __restrict__ gstart, float* __restrict__ pooled) {
    int g = blockIdx.x, t = threadIdx.x;
    __shared__ float scL[NH], shL[NH];
    __shared__ float red[256];
    if (t < NH) {
        float mu = bnsum[t] * invN;
        float var = fmaf(bnsumsq[t], invN, -mu * mu);
        float sc = gamma[t] * rsqrtf(var + 1e-5f);
        scL[t] = sc;
        shL[t] = beta[t] - mu * sc;
    }
    __syncthreads();
    int s = gstart[g], e = gstart[g + 1];
    int c = t & 127, half = t >> 7;
    float sc = scL[c], sh = shL[c];
    float pacc = 0.f;
    for (int n = s + half; n < e; n += 2) {
        size_t i = (size_t)n * NH + c;
        float r = fmaxf(fmaf(z[i], sc, sh), 0.f) + h[i];
        h[i] = r;
        hbf[i] = f2bf(r);
        pacc += r;
    }
    red[t] = pacc;
    __syncthreads();
    if (t < NH) pooled[(size_t)g * NH + t] = red[t] + red[t + NH];
}

// ---------------- pool (layer 0 only) ----------------
__global__ __launch_bounds__(256) void pool_kernel(
    const float* __restrict__ h, const int* __restrict__ gstart,
    float* __restrict__ pooled, int G) {
    int g = blockIdx.x;
    int t = threadIdx.x;
    int s = gstart[g], e = gstart[g + 1];
    int c = t & 127, half = t >> 7;
    float acc = 0.f;
    for (int n = s + half; n < e; n += 2)
        acc += h[(size_t)n * NH + c];
    __shared__ float red[256];
    red[t] = acc;
    __syncthreads();
    if (t < NH) pooled[(size_t)g * NH + t] = red[t] + red[t + NH];
}

// ---------------- JK head ----------------
__global__ void jk_kernel(const float* __restrict__ pooled, const float* __restrict__ jkW,
                          const float* __restrict__ jkb, float* __restrict__ out, int G) {
    int idx = blockIdx.x * blockDim.x + threadIdx.x;
    if (idx >= G * 10) return;
    int g = idx / 10, c = idx % 10;
    float acc = 0.f;
    for (int l = 0; l < LAYERS + 1; ++l) {
        acc += jkb[l * 10 + c];
        const float* pg = pooled + ((size_t)l * G + g) * NH;
        const float* wl = jkW + (size_t)l * NH * 10 + c;
        float s = 0.f;
#pragma unroll 16
        for (int k = 0; k < NH; ++k) s = fmaf(pg[k], wl[k * 10], s);
        acc += s;
    }
    out[idx] = acc;
}

extern "C" void kernel_launch(void* const* d_in, const int* in_sizes, int n_in,
                              void* d_out, int out_size, void* d_ws, size_t ws_size,
                              hipStream_t stream) {
    const float* h_in      = (const float*)d_in[0];
    const float* edge_attr = (const float*)d_in[1];
    const int*   edge_idx  = (const int*)d_in[2];
    const int*   batch     = (const int*)d_in[5];
    const float* emb_W     = (const float*)d_in[6];
    const float* emb_b     = (const float*)d_in[7];
    const float* conv_W    = (const float*)d_in[8];
    const float* conv_b    = (const float*)d_in[9];
    const float* conv_We   = (const float*)d_in[10];
    const float* conv_be   = (const float*)d_in[11];
    const float* bn_gamma  = (const float*)d_in[12];
    const float* bn_beta   = (const float*)d_in[13];
    const float* jk_W      = (const float*)d_in[14];
    const float* jk_b      = (const float*)d_in[15];
    float* out = (float*)d_out;

    const int N = in_sizes[0] / NH;
    const int E = in_sizes[1] / 16;
    const int G = out_size / 10;
    const int NB = (N + 1023) / 1024;

    const int* src = edge_idx;
    const int* dst = edge_idx + E;

    size_t off = 0;
    auto alloc = [&](size_t bytes) -> void* {
        void* p = (char*)d_ws + off;
        off += (bytes + 255) & ~(size_t)255;
        return p;
    };
    float* hbuf = (float*)alloc((size_t)N * NH * 4);
    unsigned short* hbf = (unsigned short*)alloc((size_t)N * NH * 2);
    float* xbuf = (float*)alloc((size_t)N * NH * 4);
    float* zbuf = (float*)alloc((size_t)N * NH * 4);
    float* pooled  = (float*)alloc((size_t)(LAYERS + 1) * G * NH * 4);
    float* easum   = (float*)alloc((size_t)N * 16 * 4);
    size_t zero_off = off;
    float* bnsum   = (float*)alloc((size_t)LAYERS * NH * 4);
    float* bnsumsq = (float*)alloc((size_t)LAYERS * NH * 4);
    int* deg       = (int*)alloc((size_t)N * 4);
    size_t zero_bytes = off - zero_off;
    int* row_start = (int*)alloc((size_t)(N + 1) * 4);
    int* cursor    = (int*)alloc((size_t)N * 4);
    int* gstart    = (int*)alloc((size_t)(G + 1) * 4);
    int* bsum      = (int*)alloc((size_t)NB * 4);
    int* srcP      = (int*)alloc((size_t)E * 4);
    int* eidP      = (int*)alloc((size_t)E * 4);
    (void)ws_size; (void)n_in;

    hipMemsetAsync((char*)d_ws + zero_off, 0, zero_bytes, stream);

    hist_kernel<<<(E + 255) / 256, 256, 0, stream>>>(dst, deg, E);
    gstart_kernel<<<(N + 255) / 256, 256, 0, stream>>>(batch, gstart, N, G);
    block_sum_kernel<<<NB, 256, 0, stream>>>(deg, bsum, N);
    scan_partials_kernel<<<1, 1024, 0, stream>>>(bsum, NB, row_start, N);
    local_scan_kernel<<<NB, 256, 0, stream>>>(deg, bsum, row_start, cursor, N);
    scatter_kernel<<<(E + 255) / 256, 256, 0, stream>>>(src, dst, cursor, srcP, eidP, E);
    easum_kernel<<<(N + 15) / 16, 256, 0, stream>>>(edge_attr, eidP, row_start, easum, N);

    dim3 gemm_grid((N + 127) / 128);
    dim3 agg_grid((N + 3) / 4);

    // embedding: writes h (fp32) and hbf (bf16 mirror)
    gemm128_kernel<<<gemm_grid, 256, 0, stream>>>(h_in, emb_W, emb_b, hbuf, N,
                                                  nullptr, nullptr, hbf);
    pool_kernel<<<G, 256, 0, stream>>>(hbuf, gstart, pooled, G);

    for (int l = 0; l < LAYERS; ++l) {
        aggregate_kernel<<<agg_grid, 256, 0, stream>>>(
            hbuf, (const unsigned*)hbf, srcP, row_start, easum,
            conv_We + (size_t)l * 16 * NH, conv_be + (size_t)l * NH, xbuf, N);
        gemm128_kernel<<<gemm_grid, 256, 0, stream>>>(
            xbuf, conv_W + (size_t)l * NH * NH, conv_b + (size_t)l * NH, zbuf, N,
            bnsum + (size_t)l * NH, bnsumsq + (size_t)l * NH, nullptr);
        update_pool_kernel<<<G, 256, 0, stream>>>(
            zbuf, hbuf, hbf, bnsum + (size_t)l * NH, bnsumsq + (size_t)l * NH,
            bn_gamma + (size_t)l * NH, bn_beta + (size_t)l * NH,
            1.0f / (float)N, gstart, pooled + (size_t)(l + 1) * G * NH);
    }

    jk_kernel<<<(G * 10 + 255) / 256, 256, 0, stream>>>(pooled, jk_W, jk_b, out, G);
}